// Round 8
// baseline (1117.721 us; speedup 1.0000x reference)
//
#include <hip/hip_runtime.h>
#include <hip/hip_bf16.h>
#include <stdint.h>

#define NDIM   64     // node channels D
#define MDIM   16     // msg channels
#define NLAYER 3
#define EIN    129    // 2D+1
#define EHD    258    // edge hidden
#define CHD    64     // coord hidden
#define NHD    128    // node hidden
#define NIN    80     // D + M
#define AB_STRIDE 512 // bytes per node in fp8 AB table (A 256B | B 256B)
#define PKT_STRIDE 32 // bytes per node packet: pos xyz f32, a2 bf16x2, b2 bf16x2
#define FP8_SCALE 1024.0f
#define NVALS  19     // 16 msg + 3 pos channels aggregated per edge

// fragment-table element counts (per layer, in bf16 elems)
#define WE1F_L (34*2*512)   // 34816
#define WN1F_L (8*3*512)    // 12288
#define WN2F_L (4*4*512)    // 8192
#define WE2F_L (9*512)      // 4608: [kt(9)][lane(64)][jj(8)] = We2[k][m]/1024
#define WC1F_L (4*512)      // 2048: [ct(4)][lane(64)][jj(8)] = Wc1[k<16][ct*16+col]

typedef float vf2 __attribute__((ext_vector_type(2)));
typedef __bf16 bf16x8 __attribute__((ext_vector_type(8)));
typedef float  f32x4  __attribute__((ext_vector_type(4)));

#define MFMA16(a, b, c) __builtin_amdgcn_mfma_f32_16x16x32_bf16((a), (b), (c), 0, 0, 0)

__device__ __forceinline__ float rcp_f(float x) { return __builtin_amdgcn_rcpf(x); }
#if __has_builtin(__builtin_amdgcn_exp2f)
__device__ __forceinline__ float exp2_f(float x) { return __builtin_amdgcn_exp2f(x); }
#else
__device__ __forceinline__ float exp2_f(float x) { return __expf(x * 0.6931471805599453f); }
#endif
__device__ __forceinline__ float silu_f(float v) {
    return v * rcp_f(1.0f + __expf(-v));
}
// h' = u * sigmoid(u/1024)  (u = 1024*pre_h); CC = -log2(e)/1024
#define CC_EXP (-1.4426950408889634f / 1024.0f)
__device__ __forceinline__ float hprime_f(float u) {
    return u * rcp_f(1.0f + exp2_f(CC_EXP * u));
}
__device__ __forceinline__ float bflo(uint32_t u) {
    union { uint32_t u; float f; } c; c.u = u << 16; return c.f;
}
__device__ __forceinline__ float bfhi(uint32_t u) {
    union { uint32_t u; float f; } c; c.u = u & 0xffff0000u; return c.f;
}
__device__ __forceinline__ uint32_t pk_fp8_4(float f0, float f1, float f2, float f3) {
    uint32_t r = (uint32_t)__builtin_amdgcn_cvt_pk_fp8_f32(f0, f1, 0, false);
    r = (uint32_t)__builtin_amdgcn_cvt_pk_fp8_f32(f2, f3, (int)r, true);
    return r;
}
__device__ __forceinline__ float clamp8(float v) {
    return fminf(448.0f, fmaxf(-448.0f, v * FP8_SCALE));
}

// ---------------- prep: weights -> MFMA fragment order (bf16) ----------------
__global__ void prep_kernel(const float* __restrict__ We1, const float* __restrict__ Wn1,
                            const float* __restrict__ Wn2, const float* __restrict__ We2,
                            const float* __restrict__ Wc1,
                            __bf16* __restrict__ WE1F, __bf16* __restrict__ WN1F,
                            __bf16* __restrict__ WN2F, __bf16* __restrict__ WE2F,
                            __bf16* __restrict__ WC1F) {
    int idx = blockIdx.x * 256 + threadIdx.x;
    const int T1 = NLAYER * WE1F_L;
    if (idx < T1) {
        int l  = idx / WE1F_L;
        int r  = idx % WE1F_L;
        int ct = r / 1024;
        int r2 = r % 1024;
        int kh = r2 / 512;
        int r3 = r2 % 512;
        int lane = r3 >> 3, jj = r3 & 7;
        int half = ct / 17, ctl = ct % 17;
        int col = ctl * 16 + (lane & 15);
        int k = kh * 32 + (lane >> 4) * 8 + jj;
        float v = 0.f;
        if (col < EHD) v = We1[((size_t)l * EIN + (half ? 64 + k : k)) * EHD + col];
        WE1F[idx] = (__bf16)v;
        return;
    }
    idx -= T1;
    const int T2 = NLAYER * WN1F_L;
    if (idx < T2) {
        int l  = idx / WN1F_L;
        int r  = idx % WN1F_L;
        int ct = r / 1536;
        int r2 = r % 1536;
        int kt = r2 / 512;
        int r3 = r2 % 512;
        int lane = r3 >> 3, jj = r3 & 7;
        int col = ct * 16 + (lane & 15);
        int k = kt * 32 + (lane >> 4) * 8 + jj;
        float v = (k < NIN) ? Wn1[((size_t)l * NIN + k) * NHD + col] : 0.f;
        WN1F[idx] = (__bf16)v;
        return;
    }
    idx -= T2;
    const int T3 = NLAYER * WN2F_L;
    if (idx < T3) {
        int l  = idx / WN2F_L;
        int r  = idx % WN2F_L;
        int ct = r / 2048;
        int r2 = r % 2048;
        int kt = r2 / 512;
        int r3 = r2 % 512;
        int lane = r3 >> 3, jj = r3 & 7;
        int col = ct * 16 + (lane & 15);
        int k = kt * 32 + (lane >> 4) * 8 + jj;
        WN2F[idx] = (__bf16)Wn2[((size_t)l * NHD + k) * NDIM + col];
        return;
    }
    idx -= T3;
    const int T4 = NLAYER * WE2F_L;
    if (idx < T4) {
        int l  = idx / WE2F_L;
        int r  = idx % WE2F_L;
        int kt = r / 512;
        int r3 = r % 512;
        int lane = r3 >> 3, jj = r3 & 7;
        int m = lane & 15;
        int k = kt * 32 + (lane >> 4) * 8 + jj;
        float v = (k < EHD) ? We2[((size_t)l * EHD + k) * MDIM + m] * (1.0f / FP8_SCALE) : 0.f;
        WE2F[idx] = (__bf16)v;
        return;
    }
    idx -= T4;
    const int T5 = NLAYER * WC1F_L;
    if (idx < T5) {
        int l  = idx / WC1F_L;
        int r  = idx % WC1F_L;
        int ct = r / 512;
        int r3 = r % 512;
        int lane = r3 >> 3, jj = r3 & 7;
        int c = ct * 16 + (lane & 15);
        int k = (lane >> 4) * 8 + jj;        // K=32 tile, only k<16 valid
        float v = (k < MDIM) ? Wc1[((size_t)l * MDIM + k) * CHD + c] : 0.f;
        WC1F[idx] = (__bf16)v;
    }
}

// ---------------- init: embedding lookup + pos copy ----------------
__global__ void init_kernel(const int* __restrict__ feats, const float* __restrict__ coors,
                            const float* __restrict__ emb,
                            float* __restrict__ x, float* __restrict__ pos, int N) {
    int idx = blockIdx.x * 256 + threadIdx.x;
    int nx = N * NDIM;
    if (idx < nx) {
        int n = idx >> 6, c = idx & 63;
        x[idx] = emb[feats[n] * NDIM + c];
    } else {
        int j = idx - nx;
        if (j < N * 3) pos[j] = coors[j];
    }
}

// ---------------- counting sort by target ----------------
__global__ void hist_kernel(const int* __restrict__ ei, int* __restrict__ cnt, int E) {
    int e = blockIdx.x * 256 + threadIdx.x;
    if (e < E) atomicAdd(&cnt[ei[E + e]], 1);
}

__global__ void scan_sum_kernel(const int* __restrict__ cnt, int* __restrict__ bsum, int N) {
    __shared__ int ws[4];
    int i = blockIdx.x * 256 + threadIdx.x;
    int v = (i < N) ? cnt[i] : 0;
    #pragma unroll
    for (int off = 32; off; off >>= 1) v += __shfl_down(v, off);
    int lane = threadIdx.x & 63, w = threadIdx.x >> 6;
    if (lane == 0) ws[w] = v;
    __syncthreads();
    if (threadIdx.x == 0) bsum[blockIdx.x] = ws[0] + ws[1] + ws[2] + ws[3];
}
__global__ void __launch_bounds__(1024) scan_top_kernel(int* __restrict__ bsum, int nb) {
    __shared__ int ws[16];
    int tid = threadIdx.x, lane = tid & 63, w = tid >> 6;
    int v = (tid < nb) ? bsum[tid] : 0;
    int sc = v;
    #pragma unroll
    for (int off = 1; off < 64; off <<= 1) {
        int u = __shfl_up(sc, off);
        if (lane >= off) sc += u;
    }
    if (lane == 63) ws[w] = sc;
    __syncthreads();
    int woff = 0;
    #pragma unroll
    for (int k = 0; k < 16; ++k) woff += (k < w) ? ws[k] : 0;
    if (tid < nb) bsum[tid] = woff + sc - v;   // exclusive
}
__global__ void scan_fin_kernel(const int* __restrict__ cnt, const int* __restrict__ bsum,
                                int* __restrict__ cursor, int N) {
    __shared__ int ws[4];
    int i = blockIdx.x * 256 + threadIdx.x;
    int tid = threadIdx.x, lane = tid & 63, w = tid >> 6;
    int v = (i < N) ? cnt[i] : 0;
    int sc = v;
    #pragma unroll
    for (int off = 1; off < 64; off <<= 1) {
        int u = __shfl_up(sc, off);
        if (lane >= off) sc += u;
    }
    if (lane == 63) ws[w] = sc;
    __syncthreads();
    int woff = 0;
    #pragma unroll
    for (int k = 0; k < 4; ++k) woff += (k < w) ? ws[k] : 0;
    if (i < N) cursor[i] = bsum[blockIdx.x] + woff + sc - v;
}

__global__ void scatter_kernel(const int* __restrict__ ei, int* __restrict__ cursor,
                               uint2* __restrict__ sorted_st, int E) {
    int e = blockIdx.x * 256 + threadIdx.x;
    if (e >= E) return;
    int s = ei[e], t = ei[E + e];
    int p = atomicAdd(&cursor[t], 1);
    uint2 st; st.x = (uint32_t)s; st.y = (uint32_t)t;
    sorted_st[p] = st;
}

// ---------------- MFMA: AB table build + agg zeroing. wave = (node16, half) ---
__global__ void __launch_bounds__(256) gemm_ab_mfma(
        const float* __restrict__ x, const float* __restrict__ pos,
        const bf16x8* __restrict__ WE1Fl, const float* __restrict__ be1l,
        uint8_t* __restrict__ A8, uint8_t* __restrict__ pkt,
        float* __restrict__ agg_msg, float* __restrict__ agg_pos, int N) {
    __shared__ __align__(16) __bf16 stg[4][16][280];
    int wave = threadIdx.x >> 6, lane = threadIdx.x & 63;
    int half = wave & 1;
    int nb = blockIdx.x * 32 + (wave >> 1) * 16;
    int lrow = lane & 15, lkg = lane >> 4;
    int row = nb + lrow; if (row >= N) row = N - 1;

    const float* xr = x + (size_t)row * NDIM + lkg * 8;
    bf16x8 a0, a1;
    #pragma unroll
    for (int j = 0; j < 8; ++j) { a0[j] = (__bf16)xr[j]; a1[j] = (__bf16)xr[32 + j]; }

    f32x4 acc[17];
    #pragma unroll
    for (int t = 0; t < 17; ++t) acc[t] = (f32x4){0.f, 0.f, 0.f, 0.f};
    const bf16x8* bf = WE1Fl + (size_t)(half * 17) * 2 * 64 + lane;
    #pragma unroll
    for (int t = 0; t < 17; ++t) {
        bf16x8 b0 = bf[(t * 2 + 0) * 64];
        bf16x8 b1 = bf[(t * 2 + 1) * 64];
        acc[t] = MFMA16(a0, b0, acc[t]);
        acc[t] = MFMA16(a1, b1, acc[t]);
    }
    #pragma unroll
    for (int t = 0; t < 17; ++t) {
        int col = t * 16 + lrow;
        float bias = (half == 0 && col < EHD) ? be1l[col] : 0.f;
        #pragma unroll
        for (int r = 0; r < 4; ++r)
            stg[wave][lkg * 4 + r][col] = (__bf16)(acc[t][r] + bias);
    }
    __syncthreads();

    int node = lane >> 2;
    int gnode = nb + node;
    const __bf16* hrow = &stg[wave][node][(lane & 3) * 64];
    if (gnode < N) {
        uint8_t* dst = A8 + (size_t)gnode * AB_STRIDE + half * 256 + (lane & 3) * 64;
        #pragma unroll
        for (int g = 0; g < 8; ++g) {
            bf16x8 hv = *(const bf16x8*)(hrow + g * 8);
            uint2 pk;
            pk.x = pk_fp8_4(clamp8((float)hv[0]), clamp8((float)hv[1]),
                            clamp8((float)hv[2]), clamp8((float)hv[3]));
            pk.y = pk_fp8_4(clamp8((float)hv[4]), clamp8((float)hv[5]),
                            clamp8((float)hv[6]), clamp8((float)hv[7]));
            *(uint2*)(dst + g * 8) = pk;
        }
    }
    if (lane < 16 && nb + lane < N) {
        int gn = nb + lane;
        const uint16_t* hr = (const uint16_t*)&stg[wave][lane][256];
        uint32_t ex = (uint32_t)hr[0] | ((uint32_t)hr[1] << 16);
        uint32_t* pk = (uint32_t*)(pkt + (size_t)gn * PKT_STRIDE);
        if (half == 0) {
            uint4 w0;
            w0.x = __float_as_uint(pos[3 * gn]);
            w0.y = __float_as_uint(pos[3 * gn + 1]);
            w0.z = __float_as_uint(pos[3 * gn + 2]);
            w0.w = ex;
            *(uint4*)pk = w0;
        } else {
            pk[4] = ex;
        }
    }
    // zero agg buffers for this block's 32-node range (replaces hipMemsetAsync)
    {
        int i16 = blockIdx.x * 512 + (int)threadIdx.x * 2;   // 32 nodes * 16 ch
        if (i16 + 1 < N * MDIM) {
            *(vf2*)(agg_msg + i16) = (vf2){0.f, 0.f};
        } else if (i16 < N * MDIM) {
            agg_msg[i16] = 0.f;
        }
        if (threadIdx.x < 96) {
            int ip = blockIdx.x * 96 + (int)threadIdx.x;     // 32 nodes * 3
            if (ip < N * 3) agg_pos[ip] = 0.f;
        }
    }
}

// ---------------- layer-0: gather AB rows from 21-row vocab table ----------------
__global__ void __launch_bounds__(256) gather_ab(
        const int* __restrict__ feats, const float* __restrict__ pos,
        const uint8_t* __restrict__ A8v, const uint8_t* __restrict__ pktv,
        uint8_t* __restrict__ A8, uint8_t* __restrict__ pkt,
        float* __restrict__ agg_msg, float* __restrict__ agg_pos, int N) {
    int nb = blockIdx.x * 8;
    int t = threadIdx.x;
    int node = nb + (t >> 5);
    int chunk = t & 31;
    if (node < N) {
        int tok = feats[node];
        const uint4* src = (const uint4*)(A8v + (size_t)tok * AB_STRIDE);
        uint4* dst = (uint4*)(A8 + (size_t)node * AB_STRIDE);
        dst[chunk] = src[chunk];                 // vocab table is L1/L2-hot
    }
    if (t < 128) {
        int i = nb * MDIM + t;                   // 8 nodes * 16 ch
        if (i < N * MDIM) agg_msg[i] = 0.f;
    } else if (t < 152) {
        int i = nb * 3 + (t - 128);
        if (i < N * 3) agg_pos[i] = 0.f;
    } else if (t < 160) {
        int n = nb + (t - 152);
        if (n < N) {
            int tok = feats[n];
            const uint32_t* pv = (const uint32_t*)(pktv + (size_t)tok * PKT_STRIDE);
            uint32_t* pk = (uint32_t*)(pkt + (size_t)n * PKT_STRIDE);
            uint4 w0;
            w0.x = __float_as_uint(pos[3 * n]);
            w0.y = __float_as_uint(pos[3 * n + 1]);
            w0.z = __float_as_uint(pos[3 * n + 2]);
            w0.w = pv[3];
            *(uint4*)pk = w0;
            pk[4] = pv[4];
        }
    }
}

// ---------------- per-edge: MFMA msg GEMM + MFMA coord + run-reduce scatter ----------------
__global__ void __launch_bounds__(256) edge_kernel(
        const uint2* __restrict__ sorted_st,
        const uint8_t* __restrict__ A8, const uint8_t* __restrict__ pkt,
        const bf16x8* __restrict__ WE2Fl, const bf16x8* __restrict__ WC1Fl,
        const float* __restrict__ be2l,
        const float* __restrict__ bc1, const float* __restrict__ Wc2,
        const float* __restrict__ bc2, const float* __restrict__ w128,
        float* __restrict__ agg_msg, float* __restrict__ agg_pos, int E) {

    __shared__ __align__(16) vf2    w128p[132];        // w128 * 1024, paired
    __shared__ __align__(16) __bf16 msg_lds[4][64][24];// [wave][edge][ch] 0-15 msg,16-18 r*cw
    __shared__ int  run_t[4][64];
    __shared__ uint run_se[4][64];

    int tid  = threadIdx.x;
    int wave = tid >> 6, lane = tid & 63;
    int kg   = lane >> 4, lrow = lane & 15;

    int base = blockIdx.x * 256 + wave * 64;
    int eo = base + lane;
    bool active = (eo < E);
    int eoc = active ? eo : (E - 1);
    uint2 st = sorted_st[eoc];
    int s_own = (int)st.x;
    int t_ld  = (int)st.y;
    int t_scan = active ? t_ld : -1;

    const uint32_t* ppt = (const uint32_t*)(pkt + (size_t)t_ld  * PKT_STRIDE);
    const uint32_t* pps = (const uint32_t*)(pkt + (size_t)s_own * PKT_STRIDE);
    uint4 pt0 = *(const uint4*)ppt;
    uint4 ps0 = *(const uint4*)pps;
    uint32_t b2o = pps[4];
    uint32_t a2o = pt0.w;
    float rx = __uint_as_float(pt0.x) - __uint_as_float(ps0.x);
    float ry = __uint_as_float(pt0.y) - __uint_as_float(ps0.y);
    float rz = __uint_as_float(pt0.z) - __uint_as_float(ps0.z);
    float d2o = rx*rx + ry*ry + rz*rz;

    // hoisted fragments / scalars (hot L1 lines)
    bf16x8 bw[9];
    #pragma unroll
    for (int kt = 0; kt < 9; ++kt) bw[kt] = WE2Fl[kt * 64 + lane];
    bf16x8 bwc[4];
    float bc1r[4], wc2r[4];
    #pragma unroll
    for (int ct = 0; ct < 4; ++ct) {
        bwc[ct]  = WC1Fl[ct * 64 + lane];
        bc1r[ct] = bc1[ct * 16 + lrow];
        wc2r[ct] = Wc2[ct * 16 + lrow];
    }
    float be2m = be2l[lrow];
    float cb2  = bc2[0];

    for (int i = tid; i < 132; i += 256) {
        int k0 = i * 2;
        float lo = (k0     < EHD) ? w128[k0]     * FP8_SCALE : 0.f;
        float hi = (k0 + 1 < EHD) ? w128[k0 + 1] * FP8_SCALE : 0.f;
        w128p[i] = (vf2){lo, hi};
    }
    __syncthreads();

    // ======== phase 1: all 4 tiles' msg GEMM (independent streams) ========
    #pragma unroll
    for (int tt = 0; tt < 4; ++tt) {
        int srcl = tt * 16 + lrow;
        int t_r = __shfl(t_ld, srcl);
        int s_r = __shfl(s_own, srcl);
        float d2r = __shfl(d2o, srcl);
        uint32_t a2r = (uint32_t)__shfl((int)a2o, srcl);
        uint32_t b2r = (uint32_t)__shfl((int)b2o, srcl);
        vf2 d2v = (vf2){d2r, d2r};

        const uint8_t* Ar = A8 + (size_t)t_r * AB_STRIDE + kg * 8;
        const uint8_t* Br = A8 + (size_t)s_r * AB_STRIDE + 256 + kg * 8;

        f32x4 acc = (f32x4){0.f, 0.f, 0.f, 0.f};
        #pragma unroll
        for (int kt = 0; kt < 8; ++kt) {
            uint2 ad = *(const uint2*)(Ar + kt * 32);
            uint2 bd = *(const uint2*)(Br + kt * 32);
            const vf2* wp = &w128p[kt * 16 + kg * 4];
            vf2 u0 = __builtin_amdgcn_cvt_pk_f32_fp8(ad.x, false)
                   + __builtin_amdgcn_cvt_pk_f32_fp8(bd.x, false) + d2v * wp[0];
            vf2 u1 = __builtin_amdgcn_cvt_pk_f32_fp8(ad.x, true)
                   + __builtin_amdgcn_cvt_pk_f32_fp8(bd.x, true)  + d2v * wp[1];
            vf2 u2 = __builtin_amdgcn_cvt_pk_f32_fp8(ad.y, false)
                   + __builtin_amdgcn_cvt_pk_f32_fp8(bd.y, false) + d2v * wp[2];
            vf2 u3 = __builtin_amdgcn_cvt_pk_f32_fp8(ad.y, true)
                   + __builtin_amdgcn_cvt_pk_f32_fp8(bd.y, true)  + d2v * wp[3];
            bf16x8 af;
            af[0] = (__bf16)hprime_f(u0.x); af[1] = (__bf16)hprime_f(u0.y);
            af[2] = (__bf16)hprime_f(u1.x); af[3] = (__bf16)hprime_f(u1.y);
            af[4] = (__bf16)hprime_f(u2.x); af[5] = (__bf16)hprime_f(u2.y);
            af[6] = (__bf16)hprime_f(u3.x); af[7] = (__bf16)hprime_f(u3.y);
            acc = MFMA16(af, bw[kt], acc);
        }
        // extras K-tile (k=256,257 nonzero only, kg==0 jj 0,1)
        {
            float h0 = 0.f, h1 = 0.f;
            if (kg == 0) {
                vf2 wx = w128p[128];
                float u0 = (bflo(a2r) + bflo(b2r)) * FP8_SCALE + d2r * wx.x;
                float u1 = (bfhi(a2r) + bfhi(b2r)) * FP8_SCALE + d2r * wx.y;
                h0 = hprime_f(u0);
                h1 = hprime_f(u1);
            }
            bf16x8 af;
            af[0] = (__bf16)h0; af[1] = (__bf16)h1;
            #pragma unroll
            for (int j = 2; j < 8; ++j) af[j] = (__bf16)0.f;
            acc = MFMA16(af, bw[8], acc);
        }
        // msg = silu(acc + be2); stash bf16 to LDS (C layout: edge=kg*4+r, m=lrow)
        #pragma unroll
        for (int r = 0; r < 4; ++r) {
            float mval = silu_f(acc[r] + be2m);
            msg_lds[wave][tt * 16 + kg * 4 + r][lrow] = (__bf16)mval;
        }
    }
    __builtin_amdgcn_wave_barrier();   // same-wave LDS producer->consumer (DS in-order)

    // ======== phase 2: all 4 tiles' coord MLP via MFMA ========
    #pragma unroll
    for (int tt = 0; tt < 4; ++tt) {
        bf16x8 ac = (bf16x8){(__bf16)0.f,(__bf16)0.f,(__bf16)0.f,(__bf16)0.f,
                             (__bf16)0.f,(__bf16)0.f,(__bf16)0.f,(__bf16)0.f};
        if (kg < 2) ac = *(const bf16x8*)&msg_lds[wave][tt * 16 + lrow][kg * 8];
        f32x4 c0 = (f32x4){0.f,0.f,0.f,0.f}, c1 = c0, c2 = c0, c3 = c0;
        c0 = MFMA16(ac, bwc[0], c0);
        c1 = MFMA16(ac, bwc[1], c1);
        c2 = MFMA16(ac, bwc[2], c2);
        c3 = MFMA16(ac, bwc[3], c3);
        // silu + Wc2 dot; C layout: edge=kg*4+r, c=ct*16+lrow
        float p0 = 0.f, p1 = 0.f, p2 = 0.f, p3 = 0.f;
        p0 += silu_f(c0[0] + bc1r[0]) * wc2r[0]; p1 += silu_f(c0[1] + bc1r[0]) * wc2r[0];
        p2 += silu_f(c0[2] + bc1r[0]) * wc2r[0]; p3 += silu_f(c0[3] + bc1r[0]) * wc2r[0];
        p0 += silu_f(c1[0] + bc1r[1]) * wc2r[1]; p1 += silu_f(c1[1] + bc1r[1]) * wc2r[1];
        p2 += silu_f(c1[2] + bc1r[1]) * wc2r[1]; p3 += silu_f(c1[3] + bc1r[1]) * wc2r[1];
        p0 += silu_f(c2[0] + bc1r[2]) * wc2r[2]; p1 += silu_f(c2[1] + bc1r[2]) * wc2r[2];
        p2 += silu_f(c2[2] + bc1r[2]) * wc2r[2]; p3 += silu_f(c2[3] + bc1r[2]) * wc2r[2];
        p0 += silu_f(c3[0] + bc1r[3]) * wc2r[3]; p1 += silu_f(c3[1] + bc1r[3]) * wc2r[3];
        p2 += silu_f(c3[2] + bc1r[3]) * wc2r[3]; p3 += silu_f(c3[3] + bc1r[3]) * wc2r[3];
        // reduce over the 16 lanes of each group (lrow axis)
        #pragma unroll
        for (int mk = 1; mk < 16; mk <<= 1) {
            p0 += __shfl_xor(p0, mk);
            p1 += __shfl_xor(p1, mk);
            p2 += __shfl_xor(p2, mk);
            p3 += __shfl_xor(p3, mk);
        }
        if (lrow < 4) {
            float sel = (lrow == 0) ? p0 : (lrow == 1) ? p1 : (lrow == 2) ? p2 : p3;
            msg_lds[wave][tt * 16 + kg * 4 + lrow][16] = (__bf16)(cb2 + sel);
        }
    }
    __builtin_amdgcn_wave_barrier();

    // ---- per-lane: r*cw into LDS cols 16..18 ----
    float cwo = (float)msg_lds[wave][lane][16];
    msg_lds[wave][lane][16] = (__bf16)(rx * cwo);
    msg_lds[wave][lane][17] = (__bf16)(ry * cwo);
    msg_lds[wave][lane][18] = (__bf16)(rz * cwo);

    // ---- run detection (sorted by t) + distributed run-sum + atomics ----
    int t_next = __shfl_down(t_scan, 1);
    bool is_end = (lane == 63) || (t_next != t_scan);
    uint64_t mask = __ballot(is_end);
    int nr = __popcll(mask);
    if (is_end) {
        uint64_t below = mask & ((1ULL << lane) - 1ULL);
        int rid = __popcll(below);
        int st2 = (below == 0ULL) ? 0 : (64 - __builtin_clzll(below));  // prev end + 1
        run_t[wave][rid]  = t_scan;
        run_se[wave][rid] = (uint)((st2 << 8) | lane);
    }
    __builtin_amdgcn_wave_barrier();

    for (int task = lane; task < nr * NVALS; task += 64) {
        int rid = task / NVALS;
        int v   = task - rid * NVALS;
        int t   = run_t[wave][rid];
        if (t >= 0) {
            uint se = run_se[wave][rid];
            int st2 = (int)(se >> 8), en = (int)(se & 0xFFu);
            float sum = 0.f;
            for (int e = st2; e <= en; ++e) sum += (float)msg_lds[wave][e][v];
            if (v < 16) atomicAdd(&agg_msg[(size_t)t * MDIM + v], sum);
            else        atomicAdd(&agg_pos[(size_t)t * 3 + (v - 16)], sum);
        }
    }
}

// ---------------- MFMA node MLP + residual + pos update ----------------
__global__ void __launch_bounds__(256) node_mfma(
        float* __restrict__ x, float* __restrict__ pos,
        const float* __restrict__ agg_msg, const float* __restrict__ agg_pos,
        const bf16x8* __restrict__ WN1Fl, const bf16x8* __restrict__ WN2Fl,
        const float* __restrict__ bn1l, const float* __restrict__ bn2l, int N) {
    __shared__ __align__(16) __bf16 stg[4][16][136];
    int wave = threadIdx.x >> 6, lane = threadIdx.x & 63;
    int nb = blockIdx.x * 64 + wave * 16;
    int lrow = lane & 15, lkg = lane >> 4;
    int row = nb + lrow;
    int rc = (row < N) ? row : (N - 1);

    const float* xr = x + (size_t)rc * NDIM + lkg * 8;
    bf16x8 a0, a1, a2;
    #pragma unroll
    for (int j = 0; j < 8; ++j) { a0[j] = (__bf16)xr[j]; a1[j] = (__bf16)xr[32 + j]; }
    if (lkg < 2) {
        const float* mr = agg_msg + (size_t)rc * MDIM + lkg * 8;
        #pragma unroll
        for (int j = 0; j < 8; ++j) a2[j] = (__bf16)mr[j];
    } else {
        #pragma unroll
        for (int j = 0; j < 8; ++j) a2[j] = (__bf16)0.f;
    }

    f32x4 h[8];
    #pragma unroll
    for (int t = 0; t < 8; ++t) h[t] = (f32x4){0.f, 0.f, 0.f, 0.f};
    const bf16x8* b1 = WN1Fl + lane;
    #pragma unroll
    for (int t = 0; t < 8; ++t) {
        h[t] = MFMA16(a0, b1[(t * 3 + 0) * 64], h[t]);
        h[t] = MFMA16(a1, b1[(t * 3 + 1) * 64], h[t]);
        h[t] = MFMA16(a2, b1[(t * 3 + 2) * 64], h[t]);
    }
    #pragma unroll
    for (int t = 0; t < 8; ++t) {
        int col = t * 16 + lrow;
        float bias = bn1l[col];
        #pragma unroll
        for (int r = 0; r < 4; ++r)
            stg[wave][lkg * 4 + r][col] = (__bf16)silu_f(h[t][r] + bias);
    }
    __syncthreads();

    bf16x8 af[4];
    #pragma unroll
    for (int kt = 0; kt < 4; ++kt)
        af[kt] = *(const bf16x8*)&stg[wave][lrow][kt * 32 + lkg * 8];

    f32x4 o[4];
    #pragma unroll
    for (int t = 0; t < 4; ++t) o[t] = (f32x4){0.f, 0.f, 0.f, 0.f};
    const bf16x8* b2 = WN2Fl + lane;
    #pragma unroll
    for (int t = 0; t < 4; ++t) {
        #pragma unroll
        for (int kt = 0; kt < 4; ++kt)
            o[t] = MFMA16(af[kt], b2[(t * 4 + kt) * 64], o[t]);
    }

    int orow = nb + lkg * 4;
    #pragma unroll
    for (int t = 0; t < 4; ++t) {
        int col = t * 16 + lrow;
        float bias = bn2l[col];
        #pragma unroll
        for (int r = 0; r < 4; ++r) {
            int rr = orow + r;
            if (rr < N) x[(size_t)rr * NDIM + col] += o[t][r] + bias;
        }
    }
    if (threadIdx.x < 192) {
        long j = (long)blockIdx.x * 192 + threadIdx.x;
        if (j < (long)N * 3) pos[j] += agg_pos[j];
    }
}

// ---------------- host launch ----------------
extern "C" void kernel_launch(void* const* d_in, const int* in_sizes, int n_in,
                              void* d_out, int out_size, void* d_ws, size_t ws_size,
                              hipStream_t stream) {
    const int*   feats = (const int*)  d_in[0];
    const float* coors = (const float*)d_in[1];
    const int*   ei    = (const int*)  d_in[2];
    const float* emb   = (const float*)d_in[3];
    const float* We1   = (const float*)d_in[4];
    const float* be1   = (const float*)d_in[5];
    const float* We2   = (const float*)d_in[6];
    const float* be2   = (const float*)d_in[7];
    const float* Wc1   = (const float*)d_in[8];
    const float* bc1   = (const float*)d_in[9];
    const float* Wc2   = (const float*)d_in[10];
    const float* bc2   = (const float*)d_in[11];
    const float* Wn1   = (const float*)d_in[12];
    const float* bn1   = (const float*)d_in[13];
    const float* Wn2   = (const float*)d_in[14];
    const float* bn2   = (const float*)d_in[15];

    const int N = in_sizes[0];
    const int E = in_sizes[2] / 2;
    const int VOCAB = in_sizes[3] / NDIM;

    float* x   = (float*)d_out;                     // [N,64]
    float* pos = (float*)d_out + (size_t)N * NDIM;  // [N,3]

    // workspace layout
    char* w = (char*)d_ws;
    uint8_t* A8 = (uint8_t*)w;                                  // N*512
    size_t off = ((size_t)N * AB_STRIDE + 255) & ~(size_t)255;
    uint8_t* pkt = (uint8_t*)(w + off);                         // N*32
    off += ((size_t)N * PKT_STRIDE + 255) & ~(size_t)255;
    float* agg_msg = (float*)(w + off);                         // N*16
    off += ((size_t)N * MDIM * 4 + 255) & ~(size_t)255;
    float* agg_pos = (float*)(w + off);                         // N*3
    off += ((size_t)N * 3 * 4 + 255) & ~(size_t)255;
    uint2* sorted_st = (uint2*)(w + off);                       // E*8
    off += ((size_t)E * 8 + 255) & ~(size_t)255;
    int* cnt = (int*)(w + off);                                 // N
    off += ((size_t)N * 4 + 255) & ~(size_t)255;
    int* cursor = (int*)(w + off);                              // N
    off += ((size_t)N * 4 + 255) & ~(size_t)255;
    int* bsum = (int*)(w + off);                                // ceil(N/256)
    off += (((size_t)N / 256 + 2) * 4 + 255) & ~(size_t)255;
    uint8_t* A8v = (uint8_t*)(w + off);                         // 32*512 vocab AB
    off += (size_t)32 * AB_STRIDE;
    uint8_t* pktv = (uint8_t*)(w + off);                        // 32*32 vocab pkt
    off += (size_t)32 * PKT_STRIDE;
    __bf16* WE1F = (__bf16*)(w + off);
    off += ((size_t)NLAYER * WE1F_L * 2 + 255) & ~(size_t)255;
    __bf16* WN1F = (__bf16*)(w + off);
    off += ((size_t)NLAYER * WN1F_L * 2 + 255) & ~(size_t)255;
    __bf16* WN2F = (__bf16*)(w + off);
    off += ((size_t)NLAYER * WN2F_L * 2 + 255) & ~(size_t)255;
    __bf16* WE2F = (__bf16*)(w + off);
    off += ((size_t)NLAYER * WE2F_L * 2 + 255) & ~(size_t)255;
    __bf16* WC1F = (__bf16*)(w + off);
    (void)ws_size; (void)n_in; (void)out_size;

    {
        int total = NLAYER * (WE1F_L + WN1F_L + WN2F_L + WE2F_L + WC1F_L);
        prep_kernel<<<(total + 255) / 256, 256, 0, stream>>>(We1, Wn1, Wn2, We2, Wc1,
                                                             WE1F, WN1F, WN2F, WE2F, WC1F);
    }
    {
        int total = N * (NDIM + 3);
        init_kernel<<<(total + 255) / 256, 256, 0, stream>>>(feats, coors, emb, x, pos, N);
    }
    // counting sort by target (once; edge_index constant across layers)
    hipMemsetAsync(cnt, 0, (size_t)N * 4, stream);
    hist_kernel<<<(E + 255) / 256, 256, 0, stream>>>(ei, cnt, E);
    {
        int nb = (N + 255) / 256;
        scan_sum_kernel<<<nb, 256, 0, stream>>>(cnt, bsum, N);
        scan_top_kernel<<<1, 1024, 0, stream>>>(bsum, nb);
        scan_fin_kernel<<<nb, 256, 0, stream>>>(cnt, bsum, cursor, N);
    }
    scatter_kernel<<<(E + 255) / 256, 256, 0, stream>>>(ei, cursor, sorted_st, E);

    for (int l = 0; l < NLAYER; ++l) {
        const float* We1_l  = We1 + (size_t)l * EIN * EHD;
        const float* w128_l = We1_l + (size_t)128 * EHD;

        if (l == 0) {
            // layer 0: x = emb[feats] -> only VOCAB distinct AB rows
            gemm_ab_mfma<<<(VOCAB + 31) / 32, 256, 0, stream>>>(
                emb, pos, (const bf16x8*)(WE1F + (size_t)l * WE1F_L),
                be1 + (size_t)l * EHD, A8v, pktv, agg_msg, agg_pos, VOCAB);
            gather_ab<<<(N + 7) / 8, 256, 0, stream>>>(
                feats, pos, A8v, pktv, A8, pkt, agg_msg, agg_pos, N);
        } else {
            gemm_ab_mfma<<<(N + 31) / 32, 256, 0, stream>>>(
                x, pos, (const bf16x8*)(WE1F + (size_t)l * WE1F_L),
                be1 + (size_t)l * EHD, A8, pkt, agg_msg, agg_pos, N);
        }

        edge_kernel<<<(E + 255) / 256, 256, 0, stream>>>(
            sorted_st, A8, pkt,
            (const bf16x8*)(WE2F + (size_t)l * WE2F_L),
            (const bf16x8*)(WC1F + (size_t)l * WC1F_L),
            be2 + (size_t)l * MDIM,
            bc1 + (size_t)l * CHD, Wc2 + (size_t)l * CHD, bc2 + l, w128_l,
            agg_msg, agg_pos, E);

        node_mfma<<<(N + 63) / 64, 256, 0, stream>>>(
            x, pos, agg_msg, agg_pos,
            (const bf16x8*)(WN1F + (size_t)l * WN1F_L),
            (const bf16x8*)(WN2F + (size_t)l * WN2F_L),
            bn1 + (size_t)l * NHD, bn2 + (size_t)l * NDIM, N);
    }
}

// Round 9
// 1021.888 us; speedup vs baseline: 1.0938x; 1.0938x over previous
//
#include <hip/hip_runtime.h>
#include <hip/hip_bf16.h>
#include <stdint.h>

#define NDIM   64     // node channels D
#define MDIM   16     // msg channels
#define NLAYER 3
#define EIN    129    // 2D+1
#define EHD    258    // edge hidden
#define CHD    64     // coord hidden
#define NHD    128    // node hidden
#define NIN    80     // D + M
#define AB_STRIDE 512 // bytes per node in fp8 AB table (A 256B | B 256B)
#define PKT_STRIDE 32 // bytes per node packet: pos xyz f32, a2 bf16x2, b2 bf16x2
#define FP8_SCALE 1024.0f
#define NVALS  19     // 16 msg + 3 pos channels aggregated per edge

// fragment-table element counts (per layer, in bf16 elems)
#define WE1F_L (34*2*512)   // 34816
#define WN1F_L (8*3*512)    // 12288
#define WN2F_L (4*4*512)    // 8192
#define WE2F_L (9*512)      // 4608: [kt(9)][lane(64)][jj(8)] = We2[k][m]/1024
#define WC1F_L (4*512)      // 2048: [ct(4)][lane(64)][jj(8)] = Wc1[k<16][ct*16+col]

typedef float vf2 __attribute__((ext_vector_type(2)));
typedef __bf16 bf16x8 __attribute__((ext_vector_type(8)));
typedef float  f32x4  __attribute__((ext_vector_type(4)));

#define MFMA16(a, b, c) __builtin_amdgcn_mfma_f32_16x16x32_bf16((a), (b), (c), 0, 0, 0)

__device__ __forceinline__ float rcp_f(float x) { return __builtin_amdgcn_rcpf(x); }
#if __has_builtin(__builtin_amdgcn_exp2f)
__device__ __forceinline__ float exp2_f(float x) { return __builtin_amdgcn_exp2f(x); }
#else
__device__ __forceinline__ float exp2_f(float x) { return __expf(x * 0.6931471805599453f); }
#endif
__device__ __forceinline__ float silu_f(float v) {
    return v * rcp_f(1.0f + __expf(-v));
}
// h' = u * sigmoid(u/1024)  (u = 1024*pre_h); CC = -log2(e)/1024
#define CC_EXP (-1.4426950408889634f / 1024.0f)
__device__ __forceinline__ float hprime_f(float u) {
    return u * rcp_f(1.0f + exp2_f(CC_EXP * u));
}
__device__ __forceinline__ float bflo(uint32_t u) {
    union { uint32_t u; float f; } c; c.u = u << 16; return c.f;
}
__device__ __forceinline__ float bfhi(uint32_t u) {
    union { uint32_t u; float f; } c; c.u = u & 0xffff0000u; return c.f;
}
__device__ __forceinline__ uint32_t pk_fp8_4(float f0, float f1, float f2, float f3) {
    uint32_t r = (uint32_t)__builtin_amdgcn_cvt_pk_fp8_f32(f0, f1, 0, false);
    r = (uint32_t)__builtin_amdgcn_cvt_pk_fp8_f32(f2, f3, (int)r, true);
    return r;
}
__device__ __forceinline__ float clamp8(float v) {
    return fminf(448.0f, fmaxf(-448.0f, v * FP8_SCALE));
}

// ---------------- prep: weights -> MFMA fragment order (bf16) ----------------
__global__ void prep_kernel(const float* __restrict__ We1, const float* __restrict__ Wn1,
                            const float* __restrict__ Wn2, const float* __restrict__ We2,
                            const float* __restrict__ Wc1,
                            __bf16* __restrict__ WE1F, __bf16* __restrict__ WN1F,
                            __bf16* __restrict__ WN2F, __bf16* __restrict__ WE2F,
                            __bf16* __restrict__ WC1F) {
    int idx = blockIdx.x * 256 + threadIdx.x;
    const int T1 = NLAYER * WE1F_L;
    if (idx < T1) {
        int l  = idx / WE1F_L;
        int r  = idx % WE1F_L;
        int ct = r / 1024;
        int r2 = r % 1024;
        int kh = r2 / 512;
        int r3 = r2 % 512;
        int lane = r3 >> 3, jj = r3 & 7;
        int half = ct / 17, ctl = ct % 17;
        int col = ctl * 16 + (lane & 15);
        int k = kh * 32 + (lane >> 4) * 8 + jj;
        float v = 0.f;
        if (col < EHD) v = We1[((size_t)l * EIN + (half ? 64 + k : k)) * EHD + col];
        WE1F[idx] = (__bf16)v;
        return;
    }
    idx -= T1;
    const int T2 = NLAYER * WN1F_L;
    if (idx < T2) {
        int l  = idx / WN1F_L;
        int r  = idx % WN1F_L;
        int ct = r / 1536;
        int r2 = r % 1536;
        int kt = r2 / 512;
        int r3 = r2 % 512;
        int lane = r3 >> 3, jj = r3 & 7;
        int col = ct * 16 + (lane & 15);
        int k = kt * 32 + (lane >> 4) * 8 + jj;
        float v = (k < NIN) ? Wn1[((size_t)l * NIN + k) * NHD + col] : 0.f;
        WN1F[idx] = (__bf16)v;
        return;
    }
    idx -= T2;
    const int T3 = NLAYER * WN2F_L;
    if (idx < T3) {
        int l  = idx / WN2F_L;
        int r  = idx % WN2F_L;
        int ct = r / 2048;
        int r2 = r % 2048;
        int kt = r2 / 512;
        int r3 = r2 % 512;
        int lane = r3 >> 3, jj = r3 & 7;
        int col = ct * 16 + (lane & 15);
        int k = kt * 32 + (lane >> 4) * 8 + jj;
        WN2F[idx] = (__bf16)Wn2[((size_t)l * NHD + k) * NDIM + col];
        return;
    }
    idx -= T3;
    const int T4 = NLAYER * WE2F_L;
    if (idx < T4) {
        int l  = idx / WE2F_L;
        int r  = idx % WE2F_L;
        int kt = r / 512;
        int r3 = r % 512;
        int lane = r3 >> 3, jj = r3 & 7;
        int m = lane & 15;
        int k = kt * 32 + (lane >> 4) * 8 + jj;
        float v = (k < EHD) ? We2[((size_t)l * EHD + k) * MDIM + m] * (1.0f / FP8_SCALE) : 0.f;
        WE2F[idx] = (__bf16)v;
        return;
    }
    idx -= T4;
    const int T5 = NLAYER * WC1F_L;
    if (idx < T5) {
        int l  = idx / WC1F_L;
        int r  = idx % WC1F_L;
        int ct = r / 512;
        int r3 = r % 512;
        int lane = r3 >> 3, jj = r3 & 7;
        int c = ct * 16 + (lane & 15);
        int k = (lane >> 4) * 8 + jj;        // K=32 tile, only k<16 valid
        float v = (k < MDIM) ? Wc1[((size_t)l * MDIM + k) * CHD + c] : 0.f;
        WC1F[idx] = (__bf16)v;
    }
}

// ---------------- init: embedding lookup + pos copy ----------------
__global__ void init_kernel(const int* __restrict__ feats, const float* __restrict__ coors,
                            const float* __restrict__ emb,
                            float* __restrict__ x, float* __restrict__ pos, int N) {
    int idx = blockIdx.x * 256 + threadIdx.x;
    int nx = N * NDIM;
    if (idx < nx) {
        int n = idx >> 6, c = idx & 63;
        x[idx] = emb[feats[n] * NDIM + c];
    } else {
        int j = idx - nx;
        if (j < N * 3) pos[j] = coors[j];
    }
}

// ---------------- counting sort by target ----------------
__global__ void hist_kernel(const int* __restrict__ ei, int* __restrict__ cnt, int E) {
    int e = blockIdx.x * 256 + threadIdx.x;
    if (e < E) atomicAdd(&cnt[ei[E + e]], 1);
}

__global__ void scan_sum_kernel(const int* __restrict__ cnt, int* __restrict__ bsum, int N) {
    __shared__ int ws[4];
    int i = blockIdx.x * 256 + threadIdx.x;
    int v = (i < N) ? cnt[i] : 0;
    #pragma unroll
    for (int off = 32; off; off >>= 1) v += __shfl_down(v, off);
    int lane = threadIdx.x & 63, w = threadIdx.x >> 6;
    if (lane == 0) ws[w] = v;
    __syncthreads();
    if (threadIdx.x == 0) bsum[blockIdx.x] = ws[0] + ws[1] + ws[2] + ws[3];
}
__global__ void __launch_bounds__(1024) scan_top_kernel(int* __restrict__ bsum, int nb) {
    __shared__ int ws[16];
    int tid = threadIdx.x, lane = tid & 63, w = tid >> 6;
    int v = (tid < nb) ? bsum[tid] : 0;
    int sc = v;
    #pragma unroll
    for (int off = 1; off < 64; off <<= 1) {
        int u = __shfl_up(sc, off);
        if (lane >= off) sc += u;
    }
    if (lane == 63) ws[w] = sc;
    __syncthreads();
    int woff = 0;
    #pragma unroll
    for (int k = 0; k < 16; ++k) woff += (k < w) ? ws[k] : 0;
    if (tid < nb) bsum[tid] = woff + sc - v;   // exclusive
}
__global__ void scan_fin_kernel(const int* __restrict__ cnt, const int* __restrict__ bsum,
                                int* __restrict__ cursor, int N) {
    __shared__ int ws[4];
    int i = blockIdx.x * 256 + threadIdx.x;
    int tid = threadIdx.x, lane = tid & 63, w = tid >> 6;
    int v = (i < N) ? cnt[i] : 0;
    int sc = v;
    #pragma unroll
    for (int off = 1; off < 64; off <<= 1) {
        int u = __shfl_up(sc, off);
        if (lane >= off) sc += u;
    }
    if (lane == 63) ws[w] = sc;
    __syncthreads();
    int woff = 0;
    #pragma unroll
    for (int k = 0; k < 4; ++k) woff += (k < w) ? ws[k] : 0;
    if (i < N) cursor[i] = bsum[blockIdx.x] + woff + sc - v;
}

__global__ void scatter_kernel(const int* __restrict__ ei, int* __restrict__ cursor,
                               uint2* __restrict__ sorted_st, int E) {
    int e = blockIdx.x * 256 + threadIdx.x;
    if (e >= E) return;
    int s = ei[e], t = ei[E + e];
    int p = atomicAdd(&cursor[t], 1);
    uint2 st; st.x = (uint32_t)s; st.y = (uint32_t)t;
    sorted_st[p] = st;
}

// ---------------- MFMA: AB table build + agg zeroing. wave = (node16, half) ---
__global__ void __launch_bounds__(256) gemm_ab_mfma(
        const float* __restrict__ x, const float* __restrict__ pos,
        const bf16x8* __restrict__ WE1Fl, const float* __restrict__ be1l,
        uint8_t* __restrict__ A8, uint8_t* __restrict__ pkt,
        float* __restrict__ agg_msg, float* __restrict__ agg_pos, int N) {
    __shared__ __align__(16) __bf16 stg[4][16][280];
    int wave = threadIdx.x >> 6, lane = threadIdx.x & 63;
    int half = wave & 1;
    int nb = blockIdx.x * 32 + (wave >> 1) * 16;
    int lrow = lane & 15, lkg = lane >> 4;
    int row = nb + lrow; if (row >= N) row = N - 1;

    const float* xr = x + (size_t)row * NDIM + lkg * 8;
    bf16x8 a0, a1;
    #pragma unroll
    for (int j = 0; j < 8; ++j) { a0[j] = (__bf16)xr[j]; a1[j] = (__bf16)xr[32 + j]; }

    f32x4 acc[17];
    #pragma unroll
    for (int t = 0; t < 17; ++t) acc[t] = (f32x4){0.f, 0.f, 0.f, 0.f};
    const bf16x8* bf = WE1Fl + (size_t)(half * 17) * 2 * 64 + lane;
    #pragma unroll
    for (int t = 0; t < 17; ++t) {
        bf16x8 b0 = bf[(t * 2 + 0) * 64];
        bf16x8 b1 = bf[(t * 2 + 1) * 64];
        acc[t] = MFMA16(a0, b0, acc[t]);
        acc[t] = MFMA16(a1, b1, acc[t]);
    }
    #pragma unroll
    for (int t = 0; t < 17; ++t) {
        int col = t * 16 + lrow;
        float bias = (half == 0 && col < EHD) ? be1l[col] : 0.f;
        #pragma unroll
        for (int r = 0; r < 4; ++r)
            stg[wave][lkg * 4 + r][col] = (__bf16)(acc[t][r] + bias);
    }
    __syncthreads();

    int node = lane >> 2;
    int gnode = nb + node;
    const __bf16* hrow = &stg[wave][node][(lane & 3) * 64];
    if (gnode < N) {
        uint8_t* dst = A8 + (size_t)gnode * AB_STRIDE + half * 256 + (lane & 3) * 64;
        #pragma unroll
        for (int g = 0; g < 8; ++g) {
            bf16x8 hv = *(const bf16x8*)(hrow + g * 8);
            uint2 pk;
            pk.x = pk_fp8_4(clamp8((float)hv[0]), clamp8((float)hv[1]),
                            clamp8((float)hv[2]), clamp8((float)hv[3]));
            pk.y = pk_fp8_4(clamp8((float)hv[4]), clamp8((float)hv[5]),
                            clamp8((float)hv[6]), clamp8((float)hv[7]));
            *(uint2*)(dst + g * 8) = pk;
        }
    }
    if (lane < 16 && nb + lane < N) {
        int gn = nb + lane;
        const uint16_t* hr = (const uint16_t*)&stg[wave][lane][256];
        uint32_t ex = (uint32_t)hr[0] | ((uint32_t)hr[1] << 16);
        uint32_t* pk = (uint32_t*)(pkt + (size_t)gn * PKT_STRIDE);
        if (half == 0) {
            uint4 w0;
            w0.x = __float_as_uint(pos[3 * gn]);
            w0.y = __float_as_uint(pos[3 * gn + 1]);
            w0.z = __float_as_uint(pos[3 * gn + 2]);
            w0.w = ex;
            *(uint4*)pk = w0;
        } else {
            pk[4] = ex;
        }
    }
    // zero agg buffers for this block's 32-node range (replaces hipMemsetAsync)
    {
        int i16 = blockIdx.x * 512 + (int)threadIdx.x * 2;   // 32 nodes * 16 ch
        if (i16 + 1 < N * MDIM) {
            *(vf2*)(agg_msg + i16) = (vf2){0.f, 0.f};
        } else if (i16 < N * MDIM) {
            agg_msg[i16] = 0.f;
        }
        if (threadIdx.x < 96) {
            int ip = blockIdx.x * 96 + (int)threadIdx.x;     // 32 nodes * 3
            if (ip < N * 3) agg_pos[ip] = 0.f;
        }
    }
}

// ---------------- layer-0: gather AB rows from 21-row vocab table ----------------
__global__ void __launch_bounds__(256) gather_ab(
        const int* __restrict__ feats, const float* __restrict__ pos,
        const uint8_t* __restrict__ A8v, const uint8_t* __restrict__ pktv,
        uint8_t* __restrict__ A8, uint8_t* __restrict__ pkt,
        float* __restrict__ agg_msg, float* __restrict__ agg_pos, int N) {
    int nb = blockIdx.x * 8;
    int t = threadIdx.x;
    int node = nb + (t >> 5);
    int chunk = t & 31;
    if (node < N) {
        int tok = feats[node];
        const uint4* src = (const uint4*)(A8v + (size_t)tok * AB_STRIDE);
        uint4* dst = (uint4*)(A8 + (size_t)node * AB_STRIDE);
        dst[chunk] = src[chunk];                 // vocab table is L1/L2-hot
    }
    if (t < 128) {
        int i = nb * MDIM + t;                   // 8 nodes * 16 ch
        if (i < N * MDIM) agg_msg[i] = 0.f;
    } else if (t < 152) {
        int i = nb * 3 + (t - 128);
        if (i < N * 3) agg_pos[i] = 0.f;
    } else if (t < 160) {
        int n = nb + (t - 152);
        if (n < N) {
            int tok = feats[n];
            const uint32_t* pv = (const uint32_t*)(pktv + (size_t)tok * PKT_STRIDE);
            uint32_t* pk = (uint32_t*)(pkt + (size_t)n * PKT_STRIDE);
            uint4 w0;
            w0.x = __float_as_uint(pos[3 * n]);
            w0.y = __float_as_uint(pos[3 * n + 1]);
            w0.z = __float_as_uint(pos[3 * n + 2]);
            w0.w = pv[3];
            *(uint4*)pk = w0;
            pk[4] = pv[4];
        }
    }
}

// ---------------- per-edge: MFMA msg GEMM + MFMA coord + run-reduce scatter ----------------
// R6-verified structure: fused per-tile msg->coord, short independent silu chains,
// VGPR 64 / 8 waves per SIMD. sig4 (R7) and phase-split (R8) both regressed this.
__global__ void __launch_bounds__(256) edge_kernel(
        const uint2* __restrict__ sorted_st,
        const uint8_t* __restrict__ A8, const uint8_t* __restrict__ pkt,
        const bf16x8* __restrict__ WE2Fl, const bf16x8* __restrict__ WC1Fl,
        const float* __restrict__ be2l,
        const float* __restrict__ bc1, const float* __restrict__ Wc2,
        const float* __restrict__ bc2, const float* __restrict__ w128,
        float* __restrict__ agg_msg, float* __restrict__ agg_pos, int E) {

    __shared__ __align__(16) vf2    w128p[132];        // w128 * 1024, paired
    __shared__ __align__(16) __bf16 msg_lds[4][64][24];// [wave][edge][ch] 0-15 msg,16-18 r*cw
    __shared__ int  run_t[4][64];
    __shared__ uint run_se[4][64];

    int tid  = threadIdx.x;
    int wave = tid >> 6, lane = tid & 63;
    int kg   = lane >> 4, lrow = lane & 15;

    int base = blockIdx.x * 256 + wave * 64;
    int eo = base + lane;
    bool active = (eo < E);
    int eoc = active ? eo : (E - 1);
    uint2 st = sorted_st[eoc];
    int s_own = (int)st.x;
    int t_ld  = (int)st.y;
    int t_scan = active ? t_ld : -1;

    const uint32_t* ppt = (const uint32_t*)(pkt + (size_t)t_ld  * PKT_STRIDE);
    const uint32_t* pps = (const uint32_t*)(pkt + (size_t)s_own * PKT_STRIDE);
    uint4 pt0 = *(const uint4*)ppt;
    uint4 ps0 = *(const uint4*)pps;
    uint32_t b2o = pps[4];
    uint32_t a2o = pt0.w;
    float rx = __uint_as_float(pt0.x) - __uint_as_float(ps0.x);
    float ry = __uint_as_float(pt0.y) - __uint_as_float(ps0.y);
    float rz = __uint_as_float(pt0.z) - __uint_as_float(ps0.z);
    float d2o = rx*rx + ry*ry + rz*rz;

    // hoisted fragments / scalars (hot L1 lines)
    bf16x8 bw[9];
    #pragma unroll
    for (int kt = 0; kt < 9; ++kt) bw[kt] = WE2Fl[kt * 64 + lane];
    bf16x8 bwc[4];
    float bc1r[4], wc2r[4];
    #pragma unroll
    for (int ct = 0; ct < 4; ++ct) {
        bwc[ct]  = WC1Fl[ct * 64 + lane];
        bc1r[ct] = bc1[ct * 16 + lrow];
        wc2r[ct] = Wc2[ct * 16 + lrow];
    }
    float be2m = be2l[lrow];
    float cb2  = bc2[0];

    for (int i = tid; i < 132; i += 256) {
        int k0 = i * 2;
        float lo = (k0     < EHD) ? w128[k0]     * FP8_SCALE : 0.f;
        float hi = (k0 + 1 < EHD) ? w128[k0 + 1] * FP8_SCALE : 0.f;
        w128p[i] = (vf2){lo, hi};
    }
    __syncthreads();

    // ---- 4 MFMA tiles of 16 edges ----
    #pragma unroll
    for (int tt = 0; tt < 4; ++tt) {
        int srcl = tt * 16 + lrow;
        int t_r = __shfl(t_ld, srcl);
        int s_r = __shfl(s_own, srcl);
        float d2r = __shfl(d2o, srcl);
        uint32_t a2r = (uint32_t)__shfl((int)a2o, srcl);
        uint32_t b2r = (uint32_t)__shfl((int)b2o, srcl);
        vf2 d2v = (vf2){d2r, d2r};

        const uint8_t* Ar = A8 + (size_t)t_r * AB_STRIDE + kg * 8;
        const uint8_t* Br = A8 + (size_t)s_r * AB_STRIDE + 256 + kg * 8;

        f32x4 acc = (f32x4){0.f, 0.f, 0.f, 0.f};
        #pragma unroll
        for (int kt = 0; kt < 8; ++kt) {
            uint2 ad = *(const uint2*)(Ar + kt * 32);
            uint2 bd = *(const uint2*)(Br + kt * 32);
            const vf2* wp = &w128p[kt * 16 + kg * 4];
            vf2 u0 = __builtin_amdgcn_cvt_pk_f32_fp8(ad.x, false)
                   + __builtin_amdgcn_cvt_pk_f32_fp8(bd.x, false) + d2v * wp[0];
            vf2 u1 = __builtin_amdgcn_cvt_pk_f32_fp8(ad.x, true)
                   + __builtin_amdgcn_cvt_pk_f32_fp8(bd.x, true)  + d2v * wp[1];
            vf2 u2 = __builtin_amdgcn_cvt_pk_f32_fp8(ad.y, false)
                   + __builtin_amdgcn_cvt_pk_f32_fp8(bd.y, false) + d2v * wp[2];
            vf2 u3 = __builtin_amdgcn_cvt_pk_f32_fp8(ad.y, true)
                   + __builtin_amdgcn_cvt_pk_f32_fp8(bd.y, true)  + d2v * wp[3];
            bf16x8 af;
            af[0] = (__bf16)hprime_f(u0.x); af[1] = (__bf16)hprime_f(u0.y);
            af[2] = (__bf16)hprime_f(u1.x); af[3] = (__bf16)hprime_f(u1.y);
            af[4] = (__bf16)hprime_f(u2.x); af[5] = (__bf16)hprime_f(u2.y);
            af[6] = (__bf16)hprime_f(u3.x); af[7] = (__bf16)hprime_f(u3.y);
            acc = MFMA16(af, bw[kt], acc);
        }
        // extras K-tile (k=256,257 nonzero only, kg==0 jj 0,1)
        {
            float h0 = 0.f, h1 = 0.f;
            if (kg == 0) {
                vf2 wx = w128p[128];
                float u0 = (bflo(a2r) + bflo(b2r)) * FP8_SCALE + d2r * wx.x;
                float u1 = (bfhi(a2r) + bfhi(b2r)) * FP8_SCALE + d2r * wx.y;
                h0 = hprime_f(u0);
                h1 = hprime_f(u1);
            }
            bf16x8 af;
            af[0] = (__bf16)h0; af[1] = (__bf16)h1;
            #pragma unroll
            for (int j = 2; j < 8; ++j) af[j] = (__bf16)0.f;
            acc = MFMA16(af, bw[8], acc);
        }
        // msg = silu(acc + be2); stash bf16 to LDS (C layout: edge=kg*4+r, m=lrow)
        #pragma unroll
        for (int r = 0; r < 4; ++r) {
            float mval = silu_f(acc[r] + be2m);
            msg_lds[wave][tt * 16 + kg * 4 + r][lrow] = (__bf16)mval;
        }
        __builtin_amdgcn_wave_barrier();   // same-wave LDS producer->consumer (DS in-order)

        // ---- coord MLP via MFMA: A = msg (16e x K=32, k<16 valid) ----
        bf16x8 ac = (bf16x8){(__bf16)0.f,(__bf16)0.f,(__bf16)0.f,(__bf16)0.f,
                             (__bf16)0.f,(__bf16)0.f,(__bf16)0.f,(__bf16)0.f};
        if (kg < 2) ac = *(const bf16x8*)&msg_lds[wave][tt * 16 + lrow][kg * 8];
        f32x4 c0 = (f32x4){0.f,0.f,0.f,0.f}, c1 = c0, c2 = c0, c3 = c0;
        c0 = MFMA16(ac, bwc[0], c0);
        c1 = MFMA16(ac, bwc[1], c1);
        c2 = MFMA16(ac, bwc[2], c2);
        c3 = MFMA16(ac, bwc[3], c3);
        // silu + Wc2 dot; C layout: edge=kg*4+r, c=ct*16+lrow
        float p0 = 0.f, p1 = 0.f, p2 = 0.f, p3 = 0.f;
        p0 += silu_f(c0[0] + bc1r[0]) * wc2r[0]; p1 += silu_f(c0[1] + bc1r[0]) * wc2r[0];
        p2 += silu_f(c0[2] + bc1r[0]) * wc2r[0]; p3 += silu_f(c0[3] + bc1r[0]) * wc2r[0];
        p0 += silu_f(c1[0] + bc1r[1]) * wc2r[1]; p1 += silu_f(c1[1] + bc1r[1]) * wc2r[1];
        p2 += silu_f(c1[2] + bc1r[1]) * wc2r[1]; p3 += silu_f(c1[3] + bc1r[1]) * wc2r[1];
        p0 += silu_f(c2[0] + bc1r[2]) * wc2r[2]; p1 += silu_f(c2[1] + bc1r[2]) * wc2r[2];
        p2 += silu_f(c2[2] + bc1r[2]) * wc2r[2]; p3 += silu_f(c2[3] + bc1r[2]) * wc2r[2];
        p0 += silu_f(c3[0] + bc1r[3]) * wc2r[3]; p1 += silu_f(c3[1] + bc1r[3]) * wc2r[3];
        p2 += silu_f(c3[2] + bc1r[3]) * wc2r[3]; p3 += silu_f(c3[3] + bc1r[3]) * wc2r[3];
        // reduce over the 16 lanes of each group (lrow axis)
        #pragma unroll
        for (int mk = 1; mk < 16; mk <<= 1) {
            p0 += __shfl_xor(p0, mk);
            p1 += __shfl_xor(p1, mk);
            p2 += __shfl_xor(p2, mk);
            p3 += __shfl_xor(p3, mk);
        }
        if (lrow < 4) {
            float sel = (lrow == 0) ? p0 : (lrow == 1) ? p1 : (lrow == 2) ? p2 : p3;
            msg_lds[wave][tt * 16 + kg * 4 + lrow][16] = (__bf16)(cb2 + sel);
        }
        __builtin_amdgcn_wave_barrier();
    }

    // ---- per-lane: r*cw into LDS cols 16..18 ----
    float cwo = (float)msg_lds[wave][lane][16];
    msg_lds[wave][lane][16] = (__bf16)(rx * cwo);
    msg_lds[wave][lane][17] = (__bf16)(ry * cwo);
    msg_lds[wave][lane][18] = (__bf16)(rz * cwo);

    // ---- run detection (sorted by t) + distributed run-sum + atomics ----
    int t_next = __shfl_down(t_scan, 1);
    bool is_end = (lane == 63) || (t_next != t_scan);
    uint64_t mask = __ballot(is_end);
    int nr = __popcll(mask);
    if (is_end) {
        uint64_t below = mask & ((1ULL << lane) - 1ULL);
        int rid = __popcll(below);
        int st2 = (below == 0ULL) ? 0 : (64 - __builtin_clzll(below));  // prev end + 1
        run_t[wave][rid]  = t_scan;
        run_se[wave][rid] = (uint)((st2 << 8) | lane);
    }
    __builtin_amdgcn_wave_barrier();

    for (int task = lane; task < nr * NVALS; task += 64) {
        int rid = task / NVALS;
        int v   = task - rid * NVALS;
        int t   = run_t[wave][rid];
        if (t >= 0) {
            uint se = run_se[wave][rid];
            int st2 = (int)(se >> 8), en = (int)(se & 0xFFu);
            float sum = 0.f;
            for (int e = st2; e <= en; ++e) sum += (float)msg_lds[wave][e][v];
            if (v < 16) atomicAdd(&agg_msg[(size_t)t * MDIM + v], sum);
            else        atomicAdd(&agg_pos[(size_t)t * 3 + (v - 16)], sum);
        }
    }
}

// ---------------- MFMA node MLP + residual + pos update ----------------
__global__ void __launch_bounds__(256) node_mfma(
        float* __restrict__ x, float* __restrict__ pos,
        const float* __restrict__ agg_msg, const float* __restrict__ agg_pos,
        const bf16x8* __restrict__ WN1Fl, const bf16x8* __restrict__ WN2Fl,
        const float* __restrict__ bn1l, const float* __restrict__ bn2l, int N) {
    __shared__ __align__(16) __bf16 stg[4][16][136];
    int wave = threadIdx.x >> 6, lane = threadIdx.x & 63;
    int nb = blockIdx.x * 64 + wave * 16;
    int lrow = lane & 15, lkg = lane >> 4;
    int row = nb + lrow;
    int rc = (row < N) ? row : (N - 1);

    const float* xr = x + (size_t)rc * NDIM + lkg * 8;
    bf16x8 a0, a1, a2;
    #pragma unroll
    for (int j = 0; j < 8; ++j) { a0[j] = (__bf16)xr[j]; a1[j] = (__bf16)xr[32 + j]; }
    if (lkg < 2) {
        const float* mr = agg_msg + (size_t)rc * MDIM + lkg * 8;
        #pragma unroll
        for (int j = 0; j < 8; ++j) a2[j] = (__bf16)mr[j];
    } else {
        #pragma unroll
        for (int j = 0; j < 8; ++j) a2[j] = (__bf16)0.f;
    }

    f32x4 h[8];
    #pragma unroll
    for (int t = 0; t < 8; ++t) h[t] = (f32x4){0.f, 0.f, 0.f, 0.f};
    const bf16x8* b1 = WN1Fl + lane;
    #pragma unroll
    for (int t = 0; t < 8; ++t) {
        h[t] = MFMA16(a0, b1[(t * 3 + 0) * 64], h[t]);
        h[t] = MFMA16(a1, b1[(t * 3 + 1) * 64], h[t]);
        h[t] = MFMA16(a2, b1[(t * 3 + 2) * 64], h[t]);
    }
    #pragma unroll
    for (int t = 0; t < 8; ++t) {
        int col = t * 16 + lrow;
        float bias = bn1l[col];
        #pragma unroll
        for (int r = 0; r < 4; ++r)
            stg[wave][lkg * 4 + r][col] = (__bf16)silu_f(h[t][r] + bias);
    }
    __syncthreads();

    bf16x8 af[4];
    #pragma unroll
    for (int kt = 0; kt < 4; ++kt)
        af[kt] = *(const bf16x8*)&stg[wave][lrow][kt * 32 + lkg * 8];

    f32x4 o[4];
    #pragma unroll
    for (int t = 0; t < 4; ++t) o[t] = (f32x4){0.f, 0.f, 0.f, 0.f};
    const bf16x8* b2 = WN2Fl + lane;
    #pragma unroll
    for (int t = 0; t < 4; ++t) {
        #pragma unroll
        for (int kt = 0; kt < 4; ++kt)
            o[t] = MFMA16(af[kt], b2[(t * 4 + kt) * 64], o[t]);
    }

    int orow = nb + lkg * 4;
    #pragma unroll
    for (int t = 0; t < 4; ++t) {
        int col = t * 16 + lrow;
        float bias = bn2l[col];
        #pragma unroll
        for (int r = 0; r < 4; ++r) {
            int rr = orow + r;
            if (rr < N) x[(size_t)rr * NDIM + col] += o[t][r] + bias;
        }
    }
    if (threadIdx.x < 192) {
        long j = (long)blockIdx.x * 192 + threadIdx.x;
        if (j < (long)N * 3) pos[j] += agg_pos[j];
    }
}

// ---------------- host launch ----------------
extern "C" void kernel_launch(void* const* d_in, const int* in_sizes, int n_in,
                              void* d_out, int out_size, void* d_ws, size_t ws_size,
                              hipStream_t stream) {
    const int*   feats = (const int*)  d_in[0];
    const float* coors = (const float*)d_in[1];
    const int*   ei    = (const int*)  d_in[2];
    const float* emb   = (const float*)d_in[3];
    const float* We1   = (const float*)d_in[4];
    const float* be1   = (const float*)d_in[5];
    const float* We2   = (const float*)d_in[6];
    const float* be2   = (const float*)d_in[7];
    const float* Wc1   = (const float*)d_in[8];
    const float* bc1   = (const float*)d_in[9];
    const float* Wc2   = (const float*)d_in[10];
    const float* bc2   = (const float*)d_in[11];
    const float* Wn1   = (const float*)d_in[12];
    const float* bn1   = (const float*)d_in[13];
    const float* Wn2   = (const float*)d_in[14];
    const float* bn2   = (const float*)d_in[15];

    const int N = in_sizes[0];
    const int E = in_sizes[2] / 2;
    const int VOCAB = in_sizes[3] / NDIM;

    float* x   = (float*)d_out;                     // [N,64]
    float* pos = (float*)d_out + (size_t)N * NDIM;  // [N,3]

    // workspace layout
    char* w = (char*)d_ws;
    uint8_t* A8 = (uint8_t*)w;                                  // N*512
    size_t off = ((size_t)N * AB_STRIDE + 255) & ~(size_t)255;
    uint8_t* pkt = (uint8_t*)(w + off);                         // N*32
    off += ((size_t)N * PKT_STRIDE + 255) & ~(size_t)255;
    float* agg_msg = (float*)(w + off);                         // N*16
    off += ((size_t)N * MDIM * 4 + 255) & ~(size_t)255;
    float* agg_pos = (float*)(w + off);                         // N*3
    off += ((size_t)N * 3 * 4 + 255) & ~(size_t)255;
    uint2* sorted_st = (uint2*)(w + off);                       // E*8
    off += ((size_t)E * 8 + 255) & ~(size_t)255;
    int* cnt = (int*)(w + off);                                 // N
    off += ((size_t)N * 4 + 255) & ~(size_t)255;
    int* cursor = (int*)(w + off);                              // N
    off += ((size_t)N * 4 + 255) & ~(size_t)255;
    int* bsum = (int*)(w + off);                                // ceil(N/256)
    off += (((size_t)N / 256 + 2) * 4 + 255) & ~(size_t)255;
    uint8_t* A8v = (uint8_t*)(w + off);                         // 32*512 vocab AB
    off += (size_t)32 * AB_STRIDE;
    uint8_t* pktv = (uint8_t*)(w + off);                        // 32*32 vocab pkt
    off += (size_t)32 * PKT_STRIDE;
    __bf16* WE1F = (__bf16*)(w + off);
    off += ((size_t)NLAYER * WE1F_L * 2 + 255) & ~(size_t)255;
    __bf16* WN1F = (__bf16*)(w + off);
    off += ((size_t)NLAYER * WN1F_L * 2 + 255) & ~(size_t)255;
    __bf16* WN2F = (__bf16*)(w + off);
    off += ((size_t)NLAYER * WN2F_L * 2 + 255) & ~(size_t)255;
    __bf16* WE2F = (__bf16*)(w + off);
    off += ((size_t)NLAYER * WE2F_L * 2 + 255) & ~(size_t)255;
    __bf16* WC1F = (__bf16*)(w + off);
    (void)ws_size; (void)n_in; (void)out_size;

    {
        int total = NLAYER * (WE1F_L + WN1F_L + WN2F_L + WE2F_L + WC1F_L);
        prep_kernel<<<(total + 255) / 256, 256, 0, stream>>>(We1, Wn1, Wn2, We2, Wc1,
                                                             WE1F, WN1F, WN2F, WE2F, WC1F);
    }
    {
        int total = N * (NDIM + 3);
        init_kernel<<<(total + 255) / 256, 256, 0, stream>>>(feats, coors, emb, x, pos, N);
    }
    // counting sort by target (once; edge_index constant across layers)
    hipMemsetAsync(cnt, 0, (size_t)N * 4, stream);
    hist_kernel<<<(E + 255) / 256, 256, 0, stream>>>(ei, cnt, E);
    {
        int nb = (N + 255) / 256;
        scan_sum_kernel<<<nb, 256, 0, stream>>>(cnt, bsum, N);
        scan_top_kernel<<<1, 1024, 0, stream>>>(bsum, nb);
        scan_fin_kernel<<<nb, 256, 0, stream>>>(cnt, bsum, cursor, N);
    }
    scatter_kernel<<<(E + 255) / 256, 256, 0, stream>>>(ei, cursor, sorted_st, E);

    for (int l = 0; l < NLAYER; ++l) {
        const float* We1_l  = We1 + (size_t)l * EIN * EHD;
        const float* w128_l = We1_l + (size_t)128 * EHD;

        if (l == 0) {
            // layer 0: x = emb[feats] -> only VOCAB distinct AB rows
            gemm_ab_mfma<<<(VOCAB + 31) / 32, 256, 0, stream>>>(
                emb, pos, (const bf16x8*)(WE1F + (size_t)l * WE1F_L),
                be1 + (size_t)l * EHD, A8v, pktv, agg_msg, agg_pos, VOCAB);
            gather_ab<<<(N + 7) / 8, 256, 0, stream>>>(
                feats, pos, A8v, pktv, A8, pkt, agg_msg, agg_pos, N);
        } else {
            gemm_ab_mfma<<<(N + 31) / 32, 256, 0, stream>>>(
                x, pos, (const bf16x8*)(WE1F + (size_t)l * WE1F_L),
                be1 + (size_t)l * EHD, A8, pkt, agg_msg, agg_pos, N);
        }

        edge_kernel<<<(E + 255) / 256, 256, 0, stream>>>(
            sorted_st, A8, pkt,
            (const bf16x8*)(WE2F + (size_t)l * WE2F_L),
            (const bf16x8*)(WC1F + (size_t)l * WC1F_L),
            be2 + (size_t)l * MDIM,
            bc1 + (size_t)l * CHD, Wc2 + (size_t)l * CHD, bc2 + l, w128_l,
            agg_msg, agg_pos, E);

        node_mfma<<<(N + 63) / 64, 256, 0, stream>>>(
            x, pos, agg_msg, agg_pos,
            (const bf16x8*)(WN1F + (size_t)l * WN1F_L),
            (const bf16x8*)(WN2F + (size_t)l * WN2F_L),
            bn1 + (size_t)l * NHD, bn2 + (size_t)l * NDIM, N);
    }
}

// Round 10
// 986.743 us; speedup vs baseline: 1.1327x; 1.0356x over previous
//
#include <hip/hip_runtime.h>
#include <hip/hip_bf16.h>
#include <stdint.h>

#define NDIM   64     // node channels D
#define MDIM   16     // msg channels
#define NLAYER 3
#define EIN    129    // 2D+1
#define EHD    258    // edge hidden
#define CHD    64     // coord hidden
#define NHD    128    // node hidden
#define NIN    80     // D + M
#define AB_STRIDE 512 // bytes per node in fp8 AB table (A 256B | B 256B)
#define PKT_STRIDE 32 // bytes per node packet: pos xyz f32, a2 bf16x2, b2 bf16x2
#define FP8_SCALE 1024.0f
#define NVALS  19     // 16 msg + 3 pos channels aggregated per edge

// fragment-table element counts (per layer, in bf16 elems)
#define WE1F_L (34*2*512)   // 34816
#define WN1F_L (8*3*512)    // 12288
#define WN2F_L (4*4*512)    // 8192
#define WE2F_L (9*512)      // 4608: [kt(9)][lane(64)][jj(8)] = We2[k][m]/1024
#define WC1F_L (4*512)      // 2048: [ct(4)][lane(64)][jj(8)] = Wc1[k<16][ct*16+col]

typedef float vf2 __attribute__((ext_vector_type(2)));
typedef __bf16 bf16x8 __attribute__((ext_vector_type(8)));
typedef float  f32x4  __attribute__((ext_vector_type(4)));

#define MFMA16(a, b, c) __builtin_amdgcn_mfma_f32_16x16x32_bf16((a), (b), (c), 0, 0, 0)

__device__ __forceinline__ float rcp_f(float x) { return __builtin_amdgcn_rcpf(x); }
#if __has_builtin(__builtin_amdgcn_exp2f)
__device__ __forceinline__ float exp2_f(float x) { return __builtin_amdgcn_exp2f(x); }
#else
__device__ __forceinline__ float exp2_f(float x) { return __expf(x * 0.6931471805599453f); }
#endif
__device__ __forceinline__ float silu_f(float v) {
    return v * rcp_f(1.0f + __expf(-v));
}
// h' = u * sigmoid(u/1024)  (u = 1024*pre_h); CC = -log2(e)/1024
#define CC_EXP (-1.4426950408889634f / 1024.0f)
__device__ __forceinline__ float hprime_f(float u) {
    return u * rcp_f(1.0f + exp2_f(CC_EXP * u));
}
__device__ __forceinline__ float bflo(uint32_t u) {
    union { uint32_t u; float f; } c; c.u = u << 16; return c.f;
}
__device__ __forceinline__ float bfhi(uint32_t u) {
    union { uint32_t u; float f; } c; c.u = u & 0xffff0000u; return c.f;
}
__device__ __forceinline__ uint32_t pk_fp8_4(float f0, float f1, float f2, float f3) {
    uint32_t r = (uint32_t)__builtin_amdgcn_cvt_pk_fp8_f32(f0, f1, 0, false);
    r = (uint32_t)__builtin_amdgcn_cvt_pk_fp8_f32(f2, f3, (int)r, true);
    return r;
}
__device__ __forceinline__ float clamp8(float v) {
    return fminf(448.0f, fmaxf(-448.0f, v * FP8_SCALE));
}

// ---------------- prep: weights -> MFMA fragment order (bf16) ----------------
__global__ void prep_kernel(const float* __restrict__ We1, const float* __restrict__ Wn1,
                            const float* __restrict__ Wn2, const float* __restrict__ We2,
                            const float* __restrict__ Wc1,
                            __bf16* __restrict__ WE1F, __bf16* __restrict__ WN1F,
                            __bf16* __restrict__ WN2F, __bf16* __restrict__ WE2F,
                            __bf16* __restrict__ WC1F) {
    int idx = blockIdx.x * 256 + threadIdx.x;
    const int T1 = NLAYER * WE1F_L;
    if (idx < T1) {
        int l  = idx / WE1F_L;
        int r  = idx % WE1F_L;
        int ct = r / 1024;
        int r2 = r % 1024;
        int kh = r2 / 512;
        int r3 = r2 % 512;
        int lane = r3 >> 3, jj = r3 & 7;
        int half = ct / 17, ctl = ct % 17;
        int col = ctl * 16 + (lane & 15);
        int k = kh * 32 + (lane >> 4) * 8 + jj;
        float v = 0.f;
        if (col < EHD) v = We1[((size_t)l * EIN + (half ? 64 + k : k)) * EHD + col];
        WE1F[idx] = (__bf16)v;
        return;
    }
    idx -= T1;
    const int T2 = NLAYER * WN1F_L;
    if (idx < T2) {
        int l  = idx / WN1F_L;
        int r  = idx % WN1F_L;
        int ct = r / 1536;
        int r2 = r % 1536;
        int kt = r2 / 512;
        int r3 = r2 % 512;
        int lane = r3 >> 3, jj = r3 & 7;
        int col = ct * 16 + (lane & 15);
        int k = kt * 32 + (lane >> 4) * 8 + jj;
        float v = (k < NIN) ? Wn1[((size_t)l * NIN + k) * NHD + col] : 0.f;
        WN1F[idx] = (__bf16)v;
        return;
    }
    idx -= T2;
    const int T3 = NLAYER * WN2F_L;
    if (idx < T3) {
        int l  = idx / WN2F_L;
        int r  = idx % WN2F_L;
        int ct = r / 2048;
        int r2 = r % 2048;
        int kt = r2 / 512;
        int r3 = r2 % 512;
        int lane = r3 >> 3, jj = r3 & 7;
        int col = ct * 16 + (lane & 15);
        int k = kt * 32 + (lane >> 4) * 8 + jj;
        WN2F[idx] = (__bf16)Wn2[((size_t)l * NHD + k) * NDIM + col];
        return;
    }
    idx -= T3;
    const int T4 = NLAYER * WE2F_L;
    if (idx < T4) {
        int l  = idx / WE2F_L;
        int r  = idx % WE2F_L;
        int kt = r / 512;
        int r3 = r % 512;
        int lane = r3 >> 3, jj = r3 & 7;
        int m = lane & 15;
        int k = kt * 32 + (lane >> 4) * 8 + jj;
        float v = (k < EHD) ? We2[((size_t)l * EHD + k) * MDIM + m] * (1.0f / FP8_SCALE) : 0.f;
        WE2F[idx] = (__bf16)v;
        return;
    }
    idx -= T4;
    const int T5 = NLAYER * WC1F_L;
    if (idx < T5) {
        int l  = idx / WC1F_L;
        int r  = idx % WC1F_L;
        int ct = r / 512;
        int r3 = r % 512;
        int lane = r3 >> 3, jj = r3 & 7;
        int c = ct * 16 + (lane & 15);
        int k = (lane >> 4) * 8 + jj;        // K=32 tile, only k<16 valid
        float v = (k < MDIM) ? Wc1[((size_t)l * MDIM + k) * CHD + c] : 0.f;
        WC1F[idx] = (__bf16)v;
    }
}

// ---------------- init: embedding lookup + pos copy ----------------
__global__ void init_kernel(const int* __restrict__ feats, const float* __restrict__ coors,
                            const float* __restrict__ emb,
                            float* __restrict__ x, float* __restrict__ pos, int N) {
    int idx = blockIdx.x * 256 + threadIdx.x;
    int nx = N * NDIM;
    if (idx < nx) {
        int n = idx >> 6, c = idx & 63;
        x[idx] = emb[feats[n] * NDIM + c];
    } else {
        int j = idx - nx;
        if (j < N * 3) pos[j] = coors[j];
    }
}

// ---------------- counting sort by target ----------------
__global__ void hist_kernel(const int* __restrict__ ei, int* __restrict__ cnt, int E) {
    int e = blockIdx.x * 256 + threadIdx.x;
    if (e < E) atomicAdd(&cnt[ei[E + e]], 1);
}

__global__ void scan_sum_kernel(const int* __restrict__ cnt, int* __restrict__ bsum, int N) {
    __shared__ int ws[4];
    int i = blockIdx.x * 256 + threadIdx.x;
    int v = (i < N) ? cnt[i] : 0;
    #pragma unroll
    for (int off = 32; off; off >>= 1) v += __shfl_down(v, off);
    int lane = threadIdx.x & 63, w = threadIdx.x >> 6;
    if (lane == 0) ws[w] = v;
    __syncthreads();
    if (threadIdx.x == 0) bsum[blockIdx.x] = ws[0] + ws[1] + ws[2] + ws[3];
}
__global__ void __launch_bounds__(1024) scan_top_kernel(int* __restrict__ bsum, int nb) {
    __shared__ int ws[16];
    int tid = threadIdx.x, lane = tid & 63, w = tid >> 6;
    int v = (tid < nb) ? bsum[tid] : 0;
    int sc = v;
    #pragma unroll
    for (int off = 1; off < 64; off <<= 1) {
        int u = __shfl_up(sc, off);
        if (lane >= off) sc += u;
    }
    if (lane == 63) ws[w] = sc;
    __syncthreads();
    int woff = 0;
    #pragma unroll
    for (int k = 0; k < 16; ++k) woff += (k < w) ? ws[k] : 0;
    if (tid < nb) bsum[tid] = woff + sc - v;   // exclusive
}
__global__ void scan_fin_kernel(const int* __restrict__ cnt, const int* __restrict__ bsum,
                                int* __restrict__ cursor, int N) {
    __shared__ int ws[4];
    int i = blockIdx.x * 256 + threadIdx.x;
    int tid = threadIdx.x, lane = tid & 63, w = tid >> 6;
    int v = (i < N) ? cnt[i] : 0;
    int sc = v;
    #pragma unroll
    for (int off = 1; off < 64; off <<= 1) {
        int u = __shfl_up(sc, off);
        if (lane >= off) sc += u;
    }
    if (lane == 63) ws[w] = sc;
    __syncthreads();
    int woff = 0;
    #pragma unroll
    for (int k = 0; k < 4; ++k) woff += (k < w) ? ws[k] : 0;
    if (i < N) cursor[i] = bsum[blockIdx.x] + woff + sc - v;
}

__global__ void scatter_kernel(const int* __restrict__ ei, int* __restrict__ cursor,
                               uint2* __restrict__ sorted_st, int E) {
    int e = blockIdx.x * 256 + threadIdx.x;
    if (e >= E) return;
    int s = ei[e], t = ei[E + e];
    int p = atomicAdd(&cursor[t], 1);
    uint2 st; st.x = (uint32_t)s; st.y = (uint32_t)t;
    sorted_st[p] = st;
}

// ---------------- MFMA: AB table build + agg zeroing. wave = (node16, half) ---
// (used for layer-0 vocab table only)
__global__ void __launch_bounds__(256) gemm_ab_mfma(
        const float* __restrict__ x, const float* __restrict__ pos,
        const bf16x8* __restrict__ WE1Fl, const float* __restrict__ be1l,
        uint8_t* __restrict__ A8, uint8_t* __restrict__ pkt,
        float* __restrict__ agg_msg, float* __restrict__ agg_pos, int N) {
    __shared__ __align__(16) __bf16 stg[4][16][280];
    int wave = threadIdx.x >> 6, lane = threadIdx.x & 63;
    int half = wave & 1;
    int nb = blockIdx.x * 32 + (wave >> 1) * 16;
    int lrow = lane & 15, lkg = lane >> 4;
    int row = nb + lrow; if (row >= N) row = N - 1;

    const float* xr = x + (size_t)row * NDIM + lkg * 8;
    bf16x8 a0, a1;
    #pragma unroll
    for (int j = 0; j < 8; ++j) { a0[j] = (__bf16)xr[j]; a1[j] = (__bf16)xr[32 + j]; }

    f32x4 acc[17];
    #pragma unroll
    for (int t = 0; t < 17; ++t) acc[t] = (f32x4){0.f, 0.f, 0.f, 0.f};
    const bf16x8* bf = WE1Fl + (size_t)(half * 17) * 2 * 64 + lane;
    #pragma unroll
    for (int t = 0; t < 17; ++t) {
        bf16x8 b0 = bf[(t * 2 + 0) * 64];
        bf16x8 b1 = bf[(t * 2 + 1) * 64];
        acc[t] = MFMA16(a0, b0, acc[t]);
        acc[t] = MFMA16(a1, b1, acc[t]);
    }
    #pragma unroll
    for (int t = 0; t < 17; ++t) {
        int col = t * 16 + lrow;
        float bias = (half == 0 && col < EHD) ? be1l[col] : 0.f;
        #pragma unroll
        for (int r = 0; r < 4; ++r)
            stg[wave][lkg * 4 + r][col] = (__bf16)(acc[t][r] + bias);
    }
    __syncthreads();

    int node = lane >> 2;
    int gnode = nb + node;
    const __bf16* hrow = &stg[wave][node][(lane & 3) * 64];
    if (gnode < N) {
        uint8_t* dst = A8 + (size_t)gnode * AB_STRIDE + half * 256 + (lane & 3) * 64;
        #pragma unroll
        for (int g = 0; g < 8; ++g) {
            bf16x8 hv = *(const bf16x8*)(hrow + g * 8);
            uint2 pk;
            pk.x = pk_fp8_4(clamp8((float)hv[0]), clamp8((float)hv[1]),
                            clamp8((float)hv[2]), clamp8((float)hv[3]));
            pk.y = pk_fp8_4(clamp8((float)hv[4]), clamp8((float)hv[5]),
                            clamp8((float)hv[6]), clamp8((float)hv[7]));
            *(uint2*)(dst + g * 8) = pk;
        }
    }
    if (lane < 16 && nb + lane < N) {
        int gn = nb + lane;
        const uint16_t* hr = (const uint16_t*)&stg[wave][lane][256];
        uint32_t ex = (uint32_t)hr[0] | ((uint32_t)hr[1] << 16);
        uint32_t* pk = (uint32_t*)(pkt + (size_t)gn * PKT_STRIDE);
        if (half == 0) {
            uint4 w0;
            w0.x = __float_as_uint(pos[3 * gn]);
            w0.y = __float_as_uint(pos[3 * gn + 1]);
            w0.z = __float_as_uint(pos[3 * gn + 2]);
            w0.w = ex;
            *(uint4*)pk = w0;
        } else {
            pk[4] = ex;
        }
    }
    // zero agg buffers for this block's 32-node range
    {
        int i16 = blockIdx.x * 512 + (int)threadIdx.x * 2;   // 32 nodes * 16 ch
        if (i16 + 1 < N * MDIM) {
            *(vf2*)(agg_msg + i16) = (vf2){0.f, 0.f};
        } else if (i16 < N * MDIM) {
            agg_msg[i16] = 0.f;
        }
        if (threadIdx.x < 96) {
            int ip = blockIdx.x * 96 + (int)threadIdx.x;     // 32 nodes * 3
            if (ip < N * 3) agg_pos[ip] = 0.f;
        }
    }
}

// ---------------- layer-0: gather AB rows from 21-row vocab table ----------------
__global__ void __launch_bounds__(256) gather_ab(
        const int* __restrict__ feats, const float* __restrict__ pos,
        const uint8_t* __restrict__ A8v, const uint8_t* __restrict__ pktv,
        uint8_t* __restrict__ A8, uint8_t* __restrict__ pkt,
        float* __restrict__ agg_msg, float* __restrict__ agg_pos, int N) {
    int nb = blockIdx.x * 8;
    int t = threadIdx.x;
    int node = nb + (t >> 5);
    int chunk = t & 31;
    if (node < N) {
        int tok = feats[node];
        const uint4* src = (const uint4*)(A8v + (size_t)tok * AB_STRIDE);
        uint4* dst = (uint4*)(A8 + (size_t)node * AB_STRIDE);
        dst[chunk] = src[chunk];                 // vocab table is L1/L2-hot
    }
    if (t < 128) {
        int i = nb * MDIM + t;                   // 8 nodes * 16 ch
        if (i < N * MDIM) agg_msg[i] = 0.f;
    } else if (t < 152) {
        int i = nb * 3 + (t - 128);
        if (i < N * 3) agg_pos[i] = 0.f;
    } else if (t < 160) {
        int n = nb + (t - 152);
        if (n < N) {
            int tok = feats[n];
            const uint32_t* pv = (const uint32_t*)(pktv + (size_t)tok * PKT_STRIDE);
            uint32_t* pk = (uint32_t*)(pkt + (size_t)n * PKT_STRIDE);
            uint4 w0;
            w0.x = __float_as_uint(pos[3 * n]);
            w0.y = __float_as_uint(pos[3 * n + 1]);
            w0.z = __float_as_uint(pos[3 * n + 2]);
            w0.w = pv[3];
            *(uint4*)pk = w0;
            pk[4] = pv[4];
        }
    }
}

// ---------------- per-edge: MFMA msg GEMM + MFMA coord + run-reduce scatter ----------------
// R6-verified structure: fused per-tile msg->coord, short independent silu chains,
// VGPR 64 / 8 waves per SIMD. sig4 (R7) and phase-split (R8) both regressed this. FROZEN.
__global__ void __launch_bounds__(256) edge_kernel(
        const uint2* __restrict__ sorted_st,
        const uint8_t* __restrict__ A8, const uint8_t* __restrict__ pkt,
        const bf16x8* __restrict__ WE2Fl, const bf16x8* __restrict__ WC1Fl,
        const float* __restrict__ be2l,
        const float* __restrict__ bc1, const float* __restrict__ Wc2,
        const float* __restrict__ bc2, const float* __restrict__ w128,
        float* __restrict__ agg_msg, float* __restrict__ agg_pos, int E) {

    __shared__ __align__(16) vf2    w128p[132];        // w128 * 1024, paired
    __shared__ __align__(16) __bf16 msg_lds[4][64][24];// [wave][edge][ch] 0-15 msg,16-18 r*cw
    __shared__ int  run_t[4][64];
    __shared__ uint run_se[4][64];

    int tid  = threadIdx.x;
    int wave = tid >> 6, lane = tid & 63;
    int kg   = lane >> 4, lrow = lane & 15;

    int base = blockIdx.x * 256 + wave * 64;
    int eo = base + lane;
    bool active = (eo < E);
    int eoc = active ? eo : (E - 1);
    uint2 st = sorted_st[eoc];
    int s_own = (int)st.x;
    int t_ld  = (int)st.y;
    int t_scan = active ? t_ld : -1;

    const uint32_t* ppt = (const uint32_t*)(pkt + (size_t)t_ld  * PKT_STRIDE);
    const uint32_t* pps = (const uint32_t*)(pkt + (size_t)s_own * PKT_STRIDE);
    uint4 pt0 = *(const uint4*)ppt;
    uint4 ps0 = *(const uint4*)pps;
    uint32_t b2o = pps[4];
    uint32_t a2o = pt0.w;
    float rx = __uint_as_float(pt0.x) - __uint_as_float(ps0.x);
    float ry = __uint_as_float(pt0.y) - __uint_as_float(ps0.y);
    float rz = __uint_as_float(pt0.z) - __uint_as_float(ps0.z);
    float d2o = rx*rx + ry*ry + rz*rz;

    // hoisted fragments / scalars (hot L1 lines)
    bf16x8 bw[9];
    #pragma unroll
    for (int kt = 0; kt < 9; ++kt) bw[kt] = WE2Fl[kt * 64 + lane];
    bf16x8 bwc[4];
    float bc1r[4], wc2r[4];
    #pragma unroll
    for (int ct = 0; ct < 4; ++ct) {
        bwc[ct]  = WC1Fl[ct * 64 + lane];
        bc1r[ct] = bc1[ct * 16 + lrow];
        wc2r[ct] = Wc2[ct * 16 + lrow];
    }
    float be2m = be2l[lrow];
    float cb2  = bc2[0];

    for (int i = tid; i < 132; i += 256) {
        int k0 = i * 2;
        float lo = (k0     < EHD) ? w128[k0]     * FP8_SCALE : 0.f;
        float hi = (k0 + 1 < EHD) ? w128[k0 + 1] * FP8_SCALE : 0.f;
        w128p[i] = (vf2){lo, hi};
    }
    __syncthreads();

    // ---- 4 MFMA tiles of 16 edges ----
    #pragma unroll
    for (int tt = 0; tt < 4; ++tt) {
        int srcl = tt * 16 + lrow;
        int t_r = __shfl(t_ld, srcl);
        int s_r = __shfl(s_own, srcl);
        float d2r = __shfl(d2o, srcl);
        uint32_t a2r = (uint32_t)__shfl((int)a2o, srcl);
        uint32_t b2r = (uint32_t)__shfl((int)b2o, srcl);
        vf2 d2v = (vf2){d2r, d2r};

        const uint8_t* Ar = A8 + (size_t)t_r * AB_STRIDE + kg * 8;
        const uint8_t* Br = A8 + (size_t)s_r * AB_STRIDE + 256 + kg * 8;

        f32x4 acc = (f32x4){0.f, 0.f, 0.f, 0.f};
        #pragma unroll
        for (int kt = 0; kt < 8; ++kt) {
            uint2 ad = *(const uint2*)(Ar + kt * 32);
            uint2 bd = *(const uint2*)(Br + kt * 32);
            const vf2* wp = &w128p[kt * 16 + kg * 4];
            vf2 u0 = __builtin_amdgcn_cvt_pk_f32_fp8(ad.x, false)
                   + __builtin_amdgcn_cvt_pk_f32_fp8(bd.x, false) + d2v * wp[0];
            vf2 u1 = __builtin_amdgcn_cvt_pk_f32_fp8(ad.x, true)
                   + __builtin_amdgcn_cvt_pk_f32_fp8(bd.x, true)  + d2v * wp[1];
            vf2 u2 = __builtin_amdgcn_cvt_pk_f32_fp8(ad.y, false)
                   + __builtin_amdgcn_cvt_pk_f32_fp8(bd.y, false) + d2v * wp[2];
            vf2 u3 = __builtin_amdgcn_cvt_pk_f32_fp8(ad.y, true)
                   + __builtin_amdgcn_cvt_pk_f32_fp8(bd.y, true)  + d2v * wp[3];
            bf16x8 af;
            af[0] = (__bf16)hprime_f(u0.x); af[1] = (__bf16)hprime_f(u0.y);
            af[2] = (__bf16)hprime_f(u1.x); af[3] = (__bf16)hprime_f(u1.y);
            af[4] = (__bf16)hprime_f(u2.x); af[5] = (__bf16)hprime_f(u2.y);
            af[6] = (__bf16)hprime_f(u3.x); af[7] = (__bf16)hprime_f(u3.y);
            acc = MFMA16(af, bw[kt], acc);
        }
        // extras K-tile (k=256,257 nonzero only, kg==0 jj 0,1)
        {
            float h0 = 0.f, h1 = 0.f;
            if (kg == 0) {
                vf2 wx = w128p[128];
                float u0 = (bflo(a2r) + bflo(b2r)) * FP8_SCALE + d2r * wx.x;
                float u1 = (bfhi(a2r) + bfhi(b2r)) * FP8_SCALE + d2r * wx.y;
                h0 = hprime_f(u0);
                h1 = hprime_f(u1);
            }
            bf16x8 af;
            af[0] = (__bf16)h0; af[1] = (__bf16)h1;
            #pragma unroll
            for (int j = 2; j < 8; ++j) af[j] = (__bf16)0.f;
            acc = MFMA16(af, bw[8], acc);
        }
        // msg = silu(acc + be2); stash bf16 to LDS (C layout: edge=kg*4+r, m=lrow)
        #pragma unroll
        for (int r = 0; r < 4; ++r) {
            float mval = silu_f(acc[r] + be2m);
            msg_lds[wave][tt * 16 + kg * 4 + r][lrow] = (__bf16)mval;
        }
        __builtin_amdgcn_wave_barrier();   // same-wave LDS producer->consumer (DS in-order)

        // ---- coord MLP via MFMA: A = msg (16e x K=32, k<16 valid) ----
        bf16x8 ac = (bf16x8){(__bf16)0.f,(__bf16)0.f,(__bf16)0.f,(__bf16)0.f,
                             (__bf16)0.f,(__bf16)0.f,(__bf16)0.f,(__bf16)0.f};
        if (kg < 2) ac = *(const bf16x8*)&msg_lds[wave][tt * 16 + lrow][kg * 8];
        f32x4 c0 = (f32x4){0.f,0.f,0.f,0.f}, c1 = c0, c2 = c0, c3 = c0;
        c0 = MFMA16(ac, bwc[0], c0);
        c1 = MFMA16(ac, bwc[1], c1);
        c2 = MFMA16(ac, bwc[2], c2);
        c3 = MFMA16(ac, bwc[3], c3);
        // silu + Wc2 dot; C layout: edge=kg*4+r, c=ct*16+lrow
        float p0 = 0.f, p1 = 0.f, p2 = 0.f, p3 = 0.f;
        p0 += silu_f(c0[0] + bc1r[0]) * wc2r[0]; p1 += silu_f(c0[1] + bc1r[0]) * wc2r[0];
        p2 += silu_f(c0[2] + bc1r[0]) * wc2r[0]; p3 += silu_f(c0[3] + bc1r[0]) * wc2r[0];
        p0 += silu_f(c1[0] + bc1r[1]) * wc2r[1]; p1 += silu_f(c1[1] + bc1r[1]) * wc2r[1];
        p2 += silu_f(c1[2] + bc1r[1]) * wc2r[1]; p3 += silu_f(c1[3] + bc1r[1]) * wc2r[1];
        p0 += silu_f(c2[0] + bc1r[2]) * wc2r[2]; p1 += silu_f(c2[1] + bc1r[2]) * wc2r[2];
        p2 += silu_f(c2[2] + bc1r[2]) * wc2r[2]; p3 += silu_f(c2[3] + bc1r[2]) * wc2r[2];
        p0 += silu_f(c3[0] + bc1r[3]) * wc2r[3]; p1 += silu_f(c3[1] + bc1r[3]) * wc2r[3];
        p2 += silu_f(c3[2] + bc1r[3]) * wc2r[3]; p3 += silu_f(c3[3] + bc1r[3]) * wc2r[3];
        // reduce over the 16 lanes of each group (lrow axis)
        #pragma unroll
        for (int mk = 1; mk < 16; mk <<= 1) {
            p0 += __shfl_xor(p0, mk);
            p1 += __shfl_xor(p1, mk);
            p2 += __shfl_xor(p2, mk);
            p3 += __shfl_xor(p3, mk);
        }
        if (lrow < 4) {
            float sel = (lrow == 0) ? p0 : (lrow == 1) ? p1 : (lrow == 2) ? p2 : p3;
            msg_lds[wave][tt * 16 + kg * 4 + lrow][16] = (__bf16)(cb2 + sel);
        }
        __builtin_amdgcn_wave_barrier();
    }

    // ---- per-lane: r*cw into LDS cols 16..18 ----
    float cwo = (float)msg_lds[wave][lane][16];
    msg_lds[wave][lane][16] = (__bf16)(rx * cwo);
    msg_lds[wave][lane][17] = (__bf16)(ry * cwo);
    msg_lds[wave][lane][18] = (__bf16)(rz * cwo);

    // ---- run detection (sorted by t) + distributed run-sum + atomics ----
    int t_next = __shfl_down(t_scan, 1);
    bool is_end = (lane == 63) || (t_next != t_scan);
    uint64_t mask = __ballot(is_end);
    int nr = __popcll(mask);
    if (is_end) {
        uint64_t below = mask & ((1ULL << lane) - 1ULL);
        int rid = __popcll(below);
        int st2 = (below == 0ULL) ? 0 : (64 - __builtin_clzll(below));  // prev end + 1
        run_t[wave][rid]  = t_scan;
        run_se[wave][rid] = (uint)((st2 << 8) | lane);
    }
    __builtin_amdgcn_wave_barrier();

    for (int task = lane; task < nr * NVALS; task += 64) {
        int rid = task / NVALS;
        int v   = task - rid * NVALS;
        int t   = run_t[wave][rid];
        if (t >= 0) {
            uint se = run_se[wave][rid];
            int st2 = (int)(se >> 8), en = (int)(se & 0xFFu);
            float sum = 0.f;
            for (int e = st2; e <= en; ++e) sum += (float)msg_lds[wave][e][v];
            if (v < 16) atomicAdd(&agg_msg[(size_t)t * MDIM + v], sum);
            else        atomicAdd(&agg_pos[(size_t)t * 3 + (v - 16)], sum);
        }
    }
}

// ---------------- MFMA node MLP + residual + pos update (final layer) ----------------
__global__ void __launch_bounds__(256) node_mfma(
        float* __restrict__ x, float* __restrict__ pos,
        const float* __restrict__ agg_msg, const float* __restrict__ agg_pos,
        const bf16x8* __restrict__ WN1Fl, const bf16x8* __restrict__ WN2Fl,
        const float* __restrict__ bn1l, const float* __restrict__ bn2l, int N) {
    __shared__ __align__(16) __bf16 stg[4][16][136];
    int wave = threadIdx.x >> 6, lane = threadIdx.x & 63;
    int nb = blockIdx.x * 64 + wave * 16;
    int lrow = lane & 15, lkg = lane >> 4;
    int row = nb + lrow;
    int rc = (row < N) ? row : (N - 1);

    const float* xr = x + (size_t)rc * NDIM + lkg * 8;
    bf16x8 a0, a1, a2;
    #pragma unroll
    for (int j = 0; j < 8; ++j) { a0[j] = (__bf16)xr[j]; a1[j] = (__bf16)xr[32 + j]; }
    if (lkg < 2) {
        const float* mr = agg_msg + (size_t)rc * MDIM + lkg * 8;
        #pragma unroll
        for (int j = 0; j < 8; ++j) a2[j] = (__bf16)mr[j];
    } else {
        #pragma unroll
        for (int j = 0; j < 8; ++j) a2[j] = (__bf16)0.f;
    }

    f32x4 h[8];
    #pragma unroll
    for (int t = 0; t < 8; ++t) h[t] = (f32x4){0.f, 0.f, 0.f, 0.f};
    const bf16x8* b1 = WN1Fl + lane;
    #pragma unroll
    for (int t = 0; t < 8; ++t) {
        h[t] = MFMA16(a0, b1[(t * 3 + 0) * 64], h[t]);
        h[t] = MFMA16(a1, b1[(t * 3 + 1) * 64], h[t]);
        h[t] = MFMA16(a2, b1[(t * 3 + 2) * 64], h[t]);
    }
    #pragma unroll
    for (int t = 0; t < 8; ++t) {
        int col = t * 16 + lrow;
        float bias = bn1l[col];
        #pragma unroll
        for (int r = 0; r < 4; ++r)
            stg[wave][lkg * 4 + r][col] = (__bf16)silu_f(h[t][r] + bias);
    }
    __syncthreads();

    bf16x8 af[4];
    #pragma unroll
    for (int kt = 0; kt < 4; ++kt)
        af[kt] = *(const bf16x8*)&stg[wave][lrow][kt * 32 + lkg * 8];

    f32x4 o[4];
    #pragma unroll
    for (int t = 0; t < 4; ++t) o[t] = (f32x4){0.f, 0.f, 0.f, 0.f};
    const bf16x8* b2 = WN2Fl + lane;
    #pragma unroll
    for (int t = 0; t < 4; ++t) {
        #pragma unroll
        for (int kt = 0; kt < 4; ++kt)
            o[t] = MFMA16(af[kt], b2[(t * 4 + kt) * 64], o[t]);
    }

    int orow = nb + lkg * 4;
    #pragma unroll
    for (int t = 0; t < 4; ++t) {
        int col = t * 16 + lrow;
        float bias = bn2l[col];
        #pragma unroll
        for (int r = 0; r < 4; ++r) {
            int rr = orow + r;
            if (rr < N) x[(size_t)rr * NDIM + col] += o[t][r] + bias;
        }
    }
    if (threadIdx.x < 192) {
        long j = (long)blockIdx.x * 192 + threadIdx.x;
        if (j < (long)N * 3) pos[j] += agg_pos[j];
    }
}

// ---------------- FUSED: node MLP (layer l) + AB build (layer l+1) ----------------
// 64 nodes/block, 4 waves; each wave owns 16 nodes end-to-end.
__global__ void __launch_bounds__(256) node_gemm_fused(
        float* __restrict__ x, float* __restrict__ pos,
        const float* __restrict__ agg_msg, const float* __restrict__ agg_pos,
        const bf16x8* __restrict__ WN1Fl, const bf16x8* __restrict__ WN2Fl,
        const float* __restrict__ bn1l, const float* __restrict__ bn2l,
        const bf16x8* __restrict__ WE1Fn, const float* __restrict__ be1n,
        uint8_t* __restrict__ A8, uint8_t* __restrict__ pkt, int N) {
    __shared__ __align__(16) __bf16 stg[4][16][280];
    int wave = threadIdx.x >> 6, lane = threadIdx.x & 63;
    int nb = blockIdx.x * 64 + wave * 16;
    int lrow = lane & 15, lkg = lane >> 4;
    int row = nb + lrow;
    int rc = (row < N) ? row : (N - 1);

    // ======== node phase ========
    const float* xr = x + (size_t)rc * NDIM + lkg * 8;
    bf16x8 a0, a1, a2;
    #pragma unroll
    for (int j = 0; j < 8; ++j) { a0[j] = (__bf16)xr[j]; a1[j] = (__bf16)xr[32 + j]; }
    if (lkg < 2) {
        const float* mr = agg_msg + (size_t)rc * MDIM + lkg * 8;
        #pragma unroll
        for (int j = 0; j < 8; ++j) a2[j] = (__bf16)mr[j];
    } else {
        #pragma unroll
        for (int j = 0; j < 8; ++j) a2[j] = (__bf16)0.f;
    }

    f32x4 h[8];
    #pragma unroll
    for (int t = 0; t < 8; ++t) h[t] = (f32x4){0.f, 0.f, 0.f, 0.f};
    const bf16x8* b1 = WN1Fl + lane;
    #pragma unroll
    for (int t = 0; t < 8; ++t) {
        h[t] = MFMA16(a0, b1[(t * 3 + 0) * 64], h[t]);
        h[t] = MFMA16(a1, b1[(t * 3 + 1) * 64], h[t]);
        h[t] = MFMA16(a2, b1[(t * 3 + 2) * 64], h[t]);
    }
    #pragma unroll
    for (int t = 0; t < 8; ++t) {
        int col = t * 16 + lrow;
        float bias = bn1l[col];
        #pragma unroll
        for (int r = 0; r < 4; ++r)
            stg[wave][lkg * 4 + r][col] = (__bf16)silu_f(h[t][r] + bias);
    }
    __builtin_amdgcn_wave_barrier();

    bf16x8 af[4];
    #pragma unroll
    for (int kt = 0; kt < 4; ++kt)
        af[kt] = *(const bf16x8*)&stg[wave][lrow][kt * 32 + lkg * 8];

    f32x4 o[4];
    #pragma unroll
    for (int t = 0; t < 4; ++t) o[t] = (f32x4){0.f, 0.f, 0.f, 0.f};
    const bf16x8* b2 = WN2Fl + lane;
    #pragma unroll
    for (int t = 0; t < 4; ++t) {
        #pragma unroll
        for (int kt = 0; kt < 4; ++kt)
            o[t] = MFMA16(af[kt], b2[(t * 4 + kt) * 64], o[t]);
    }
    __builtin_amdgcn_wave_barrier();   // af reads done before stg overwrite

    // write new x (global f32, residual) + stage new x bf16 to LDS for gemm A
    int orow = nb + lkg * 4;
    #pragma unroll
    for (int t = 0; t < 4; ++t) {
        int col = t * 16 + lrow;
        float bias = bn2l[col];
        #pragma unroll
        for (int r = 0; r < 4; ++r) {
            int rr = orow + r;
            int rrc = (rr < N) ? rr : (N - 1);
            float xv = x[(size_t)rrc * NDIM + col] + o[t][r] + bias;
            if (rr < N) x[(size_t)rr * NDIM + col] = xv;
            stg[wave][lkg * 4 + r][col] = (__bf16)xv;
        }
    }
    // pos update (block's 64 nodes * 3) — must complete before pkt build
    if (threadIdx.x < 192) {
        long j = (long)blockIdx.x * 192 + threadIdx.x;
        if (j < (long)N * 3) pos[j] += agg_pos[j];
    }
    __syncthreads();

    // ======== gemm phase: AB table for layer l+1 ========
    bf16x8 g0 = *(const bf16x8*)&stg[wave][lrow][lkg * 8];
    bf16x8 g1 = *(const bf16x8*)&stg[wave][lrow][32 + lkg * 8];
    __builtin_amdgcn_wave_barrier();

    int node = lane >> 2;
    int gnode = nb + node;
    #pragma unroll
    for (int half = 0; half < 2; ++half) {
        f32x4 acc[17];
        #pragma unroll
        for (int t = 0; t < 17; ++t) acc[t] = (f32x4){0.f, 0.f, 0.f, 0.f};
        const bf16x8* bf = WE1Fn + (size_t)(half * 17) * 2 * 64 + lane;
        #pragma unroll
        for (int t = 0; t < 17; ++t) {
            bf16x8 b0 = bf[(t * 2 + 0) * 64];
            bf16x8 bb1 = bf[(t * 2 + 1) * 64];
            acc[t] = MFMA16(g0, b0, acc[t]);
            acc[t] = MFMA16(g1, bb1, acc[t]);
        }
        #pragma unroll
        for (int t = 0; t < 17; ++t) {
            int col = t * 16 + lrow;
            float bias = (half == 0 && col < EHD) ? be1n[col] : 0.f;
            #pragma unroll
            for (int r = 0; r < 4; ++r)
                stg[wave][lkg * 4 + r][col] = (__bf16)(acc[t][r] + bias);
        }
        __builtin_amdgcn_wave_barrier();

        const __bf16* hrow = &stg[wave][node][(lane & 3) * 64];
        if (gnode < N) {
            uint8_t* dst = A8 + (size_t)gnode * AB_STRIDE + half * 256 + (lane & 3) * 64;
            #pragma unroll
            for (int g = 0; g < 8; ++g) {
                bf16x8 hv = *(const bf16x8*)(hrow + g * 8);
                uint2 pk;
                pk.x = pk_fp8_4(clamp8((float)hv[0]), clamp8((float)hv[1]),
                                clamp8((float)hv[2]), clamp8((float)hv[3]));
                pk.y = pk_fp8_4(clamp8((float)hv[4]), clamp8((float)hv[5]),
                                clamp8((float)hv[6]), clamp8((float)hv[7]));
                *(uint2*)(dst + g * 8) = pk;
            }
        }
        if (lane < 16 && nb + lane < N) {
            int gn = nb + lane;
            const uint16_t* hr = (const uint16_t*)&stg[wave][lane][256];
            uint32_t ex = (uint32_t)hr[0] | ((uint32_t)hr[1] << 16);
            uint32_t* pk = (uint32_t*)(pkt + (size_t)gn * PKT_STRIDE);
            if (half == 0) {
                uint4 w0;
                w0.x = __float_as_uint(pos[3 * gn]);     // pos updated pre-syncthreads
                w0.y = __float_as_uint(pos[3 * gn + 1]);
                w0.z = __float_as_uint(pos[3 * gn + 2]);
                w0.w = ex;
                *(uint4*)pk = w0;
            } else {
                pk[4] = ex;
            }
        }
        __builtin_amdgcn_wave_barrier();
    }

    // zero agg buffers for this block's 64-node range (consumed above, reused by next edge)
    {
        long i16 = (long)blockIdx.x * 1024 + (long)threadIdx.x * 4;  // 64 nodes * 16 ch
        if (i16 + 3 < (long)N * MDIM) {
            *(f32x4*)(agg_msg + i16) = (f32x4){0.f, 0.f, 0.f, 0.f};
        } else {
            for (int q = 0; q < 4; ++q)
                if (i16 + q < (long)N * MDIM) ((float*)agg_msg)[i16 + q] = 0.f;
        }
        if (threadIdx.x < 192) {
            long ip = (long)blockIdx.x * 192 + threadIdx.x;          // 64 nodes * 3
            if (ip < (long)N * 3) ((float*)agg_pos)[ip] = 0.f;
        }
    }
}

// ---------------- host launch ----------------
extern "C" void kernel_launch(void* const* d_in, const int* in_sizes, int n_in,
                              void* d_out, int out_size, void* d_ws, size_t ws_size,
                              hipStream_t stream) {
    const int*   feats = (const int*)  d_in[0];
    const float* coors = (const float*)d_in[1];
    const int*   ei    = (const int*)  d_in[2];
    const float* emb   = (const float*)d_in[3];
    const float* We1   = (const float*)d_in[4];
    const float* be1   = (const float*)d_in[5];
    const float* We2   = (const float*)d_in[6];
    const float* be2   = (const float*)d_in[7];
    const float* Wc1   = (const float*)d_in[8];
    const float* bc1   = (const float*)d_in[9];
    const float* Wc2   = (const float*)d_in[10];
    const float* bc2   = (const float*)d_in[11];
    const float* Wn1   = (const float*)d_in[12];
    const float* bn1   = (const float*)d_in[13];
    const float* Wn2   = (const float*)d_in[14];
    const float* bn2   = (const float*)d_in[15];

    const int N = in_sizes[0];
    const int E = in_sizes[2] / 2;
    const int VOCAB = in_sizes[3] / NDIM;

    float* x   = (float*)d_out;                     // [N,64]
    float* pos = (float*)d_out + (size_t)N * NDIM;  // [N,3]

    // workspace layout
    char* w = (char*)d_ws;
    uint8_t* A8 = (uint8_t*)w;                                  // N*512
    size_t off = ((size_t)N * AB_STRIDE + 255) & ~(size_t)255;
    uint8_t* pkt = (uint8_t*)(w + off);                         // N*32
    off += ((size_t)N * PKT_STRIDE + 255) & ~(size_t)255;
    float* agg_msg = (float*)(w + off);                         // N*16
    off += ((size_t)N * MDIM * 4 + 255) & ~(size_t)255;
    float* agg_pos = (float*)(w + off);                         // N*3
    off += ((size_t)N * 3 * 4 + 255) & ~(size_t)255;
    uint2* sorted_st = (uint2*)(w + off);                       // E*8
    off += ((size_t)E * 8 + 255) & ~(size_t)255;
    int* cnt = (int*)(w + off);                                 // N
    off += ((size_t)N * 4 + 255) & ~(size_t)255;
    int* cursor = (int*)(w + off);                              // N
    off += ((size_t)N * 4 + 255) & ~(size_t)255;
    int* bsum = (int*)(w + off);                                // ceil(N/256)
    off += (((size_t)N / 256 + 2) * 4 + 255) & ~(size_t)255;
    uint8_t* A8v = (uint8_t*)(w + off);                         // 32*512 vocab AB
    off += (size_t)32 * AB_STRIDE;
    uint8_t* pktv = (uint8_t*)(w + off);                        // 32*32 vocab pkt
    off += (size_t)32 * PKT_STRIDE;
    __bf16* WE1F = (__bf16*)(w + off);
    off += ((size_t)NLAYER * WE1F_L * 2 + 255) & ~(size_t)255;
    __bf16* WN1F = (__bf16*)(w + off);
    off += ((size_t)NLAYER * WN1F_L * 2 + 255) & ~(size_t)255;
    __bf16* WN2F = (__bf16*)(w + off);
    off += ((size_t)NLAYER * WN2F_L * 2 + 255) & ~(size_t)255;
    __bf16* WE2F = (__bf16*)(w + off);
    off += ((size_t)NLAYER * WE2F_L * 2 + 255) & ~(size_t)255;
    __bf16* WC1F = (__bf16*)(w + off);
    (void)ws_size; (void)n_in; (void)out_size;

    {
        int total = NLAYER * (WE1F_L + WN1F_L + WN2F_L + WE2F_L + WC1F_L);
        prep_kernel<<<(total + 255) / 256, 256, 0, stream>>>(We1, Wn1, Wn2, We2, Wc1,
                                                             WE1F, WN1F, WN2F, WE2F, WC1F);
    }
    {
        int total = N * (NDIM + 3);
        init_kernel<<<(total + 255) / 256, 256, 0, stream>>>(feats, coors, emb, x, pos, N);
    }
    // counting sort by target (once; edge_index constant across layers)
    hipMemsetAsync(cnt, 0, (size_t)N * 4, stream);
    hist_kernel<<<(E + 255) / 256, 256, 0, stream>>>(ei, cnt, E);
    {
        int nb = (N + 255) / 256;
        scan_sum_kernel<<<nb, 256, 0, stream>>>(cnt, bsum, N);
        scan_top_kernel<<<1, 1024, 0, stream>>>(bsum, nb);
        scan_fin_kernel<<<nb, 256, 0, stream>>>(cnt, bsum, cursor, N);
    }
    scatter_kernel<<<(E + 255) / 256, 256, 0, stream>>>(ei, cursor, sorted_st, E);

    // ---- layer 0: vocab AB + gather (also zeroes agg) ----
    gemm_ab_mfma<<<(VOCAB + 31) / 32, 256, 0, stream>>>(
        emb, pos, (const bf16x8*)WE1F, be1, A8v, pktv, agg_msg, agg_pos, VOCAB);
    gather_ab<<<(N + 7) / 8, 256, 0, stream>>>(
        feats, pos, A8v, pktv, A8, pkt, agg_msg, agg_pos, N);

    for (int l = 0; l < NLAYER; ++l) {
        const float* We1_l  = We1 + (size_t)l * EIN * EHD;
        const float* w128_l = We1_l + (size_t)128 * EHD;

        edge_kernel<<<(E + 255) / 256, 256, 0, stream>>>(
            sorted_st, A8, pkt,
            (const bf16x8*)(WE2F + (size_t)l * WE2F_L),
            (const bf16x8*)(WC1F + (size_t)l * WC1F_L),
            be2 + (size_t)l * MDIM,
            bc1 + (size_t)l * CHD, Wc2 + (size_t)l * CHD, bc2 + l, w128_l,
            agg_msg, agg_pos, E);

        if (l < NLAYER - 1) {
            // fused: node MLP (layer l) + AB table build (layer l+1) + agg zeroing
            node_gemm_fused<<<(N + 63) / 64, 256, 0, stream>>>(
                x, pos, agg_msg, agg_pos,
                (const bf16x8*)(WN1F + (size_t)l * WN1F_L),
                (const bf16x8*)(WN2F + (size_t)l * WN2F_L),
                bn1 + (size_t)l * NHD, bn2 + (size_t)l * NDIM,
                (const bf16x8*)(WE1F + (size_t)(l + 1) * WE1F_L),
                be1 + (size_t)(l + 1) * EHD,
                A8, pkt, N);
        } else {
            node_mfma<<<(N + 63) / 64, 256, 0, stream>>>(
                x, pos, agg_msg, agg_pos,
                (const bf16x8*)(WN1F + (size_t)l * WN1F_L),
                (const bf16x8*)(WN2F + (size_t)l * WN2F_L),
                bn1 + (size_t)l * NHD, bn2 + (size_t)l * NDIM, N);
        }
    }
}